// Round 4
// baseline (887.137 us; speedup 1.0000x reference)
//
#include <hip/hip_runtime.h>
#include <math.h>

#define Bb 2
#define Tt 1024
#define Cc 1024
#define Hh 16
#define Dd 64
#define Mm (Bb*Tt)
#define DECAY_SCALE (-0.6065306597126334f)
#define GN_EPS (64e-5f)

typedef __attribute__((ext_vector_type(8))) short short8;   // 8 bf16 (4 VGPRs)
typedef __attribute__((ext_vector_type(4))) float f32x4;    // MFMA acc

struct GemmDesc {
  const float* A;      // used when mixrow < 0 (row stride = K)
  const float* W;      // (N, K) row-major
  float* out;          // (M, N) row-major
  const float* bias;   // per-n bias or nullptr
  int N, K;
  int mixrow;          // >=0: A = token-shift mix of hidden_states with x_mix[mixrow]
  int ep;              // 0 none, 1 tanh, 2 sigmoid(x+bias?), 3 DECAY*sigmoid(x+bias)
};

__device__ __forceinline__ float4 ld4(const float* p){ return *reinterpret_cast<const float4*>(p); }
__device__ __forceinline__ float sigmf(float x){ return 1.f/(1.f+expf(-x)); }

__device__ __forceinline__ float wredsum(float x){
  #pragma unroll
  for (int off=32; off>0; off>>=1) x += __shfl_xor(x, off);
  return x;
}

// ---------------- vector-ALU GEMM (LoRA stages only) ----------------
#define BM 64
#define BN 128
#define BK 32

__global__ __launch_bounds__(256) void gemm_kernel(
    GemmDesc d0, GemmDesc d1, GemmDesc d2, GemmDesc d3,
    const float* __restrict__ xmix, const float* __restrict__ hs)
{
  GemmDesc d = (blockIdx.z==0)?d0:(blockIdx.z==1)?d1:(blockIdx.z==2)?d2:d3;
  const int n0 = blockIdx.x * BN;
  if (n0 >= d.N) return;            // block-uniform
  const int m0 = blockIdx.y * BM;
  const int tid = threadIdx.x;
  __shared__ float As[BK][BM+4];
  __shared__ float Bs[BK][BN+4];
  const int ty = tid >> 4, tx = tid & 15;

  float acc[4][8];
  #pragma unroll
  for (int i=0;i<4;++i)
    #pragma unroll
    for (int j=0;j<8;++j) acc[i][j]=0.f;

  const int K = d.K;
  const int nt = K / BK;
  const float* mrow = (d.mixrow >= 0) ? (xmix + (size_t)d.mixrow * Cc) : nullptr;
  float4 pa[2], pb[4];

  auto load_tile = [&](int kt){
    const int kbase = kt * BK;
    #pragma unroll
    for (int u=0;u<2;++u){
      const int li = tid + u*256;
      const int ar = li >> 3;
      const int kk = ((li & 7) << 2) + kbase;
      const int gm = m0 + ar;
      if (mrow){
        float4 h0 = ld4(hs + (size_t)gm*Cc + kk);
        float4 mx = ld4(mrow + kk);
        float4 hp = make_float4(0.f,0.f,0.f,0.f);
        if ((gm & (Tt-1)) != 0) hp = ld4(hs + (size_t)(gm-1)*Cc + kk);
        pa[u].x = h0.x + (hp.x - h0.x)*mx.x;
        pa[u].y = h0.y + (hp.y - h0.y)*mx.y;
        pa[u].z = h0.z + (hp.z - h0.z)*mx.z;
        pa[u].w = h0.w + (hp.w - h0.w)*mx.w;
      } else {
        pa[u] = ld4(d.A + (size_t)gm*K + kk);
      }
    }
    #pragma unroll
    for (int u=0;u<4;++u){
      const int li = tid + u*256;
      const int br = li >> 3;
      const int kk = ((li & 7) << 2) + kbase;
      const int gn = n0 + br;
      pb[u] = (gn < d.N) ? ld4(d.W + (size_t)gn*K + kk) : make_float4(0.f,0.f,0.f,0.f);
    }
  };

  load_tile(0);
  for (int kt=0; kt<nt; ++kt){
    __syncthreads();
    #pragma unroll
    for (int u=0;u<2;++u){
      const int li = tid + u*256;
      const int ar = li >> 3;
      const int kc = (li & 7) << 2;
      As[kc+0][ar] = pa[u].x; As[kc+1][ar] = pa[u].y;
      As[kc+2][ar] = pa[u].z; As[kc+3][ar] = pa[u].w;
    }
    #pragma unroll
    for (int u=0;u<4;++u){
      const int li = tid + u*256;
      const int br = li >> 3;
      const int kc = (li & 7) << 2;
      Bs[kc+0][br] = pb[u].x; Bs[kc+1][br] = pb[u].y;
      Bs[kc+2][br] = pb[u].z; Bs[kc+3][br] = pb[u].w;
    }
    __syncthreads();
    if (kt+1 < nt) load_tile(kt+1);
    #pragma unroll
    for (int kk=0;kk<BK;++kk){
      const float4 a0 = *(const float4*)&As[kk][ty<<2];
      const float4 b0 = *(const float4*)&Bs[kk][tx<<3];
      const float4 b1 = *(const float4*)&Bs[kk][(tx<<3)+4];
      const float av[4] = {a0.x,a0.y,a0.z,a0.w};
      const float bv[8] = {b0.x,b0.y,b0.z,b0.w,b1.x,b1.y,b1.z,b1.w};
      #pragma unroll
      for (int i=0;i<4;++i)
        #pragma unroll
        for (int j=0;j<8;++j)
          acc[i][j] = fmaf(av[i], bv[j], acc[i][j]);
    }
  }

  const int ep = d.ep;
  #pragma unroll
  for (int i=0;i<4;++i){
    const int gm = m0 + (ty<<2) + i;
    float* orow = d.out + (size_t)gm * d.N;
    #pragma unroll
    for (int j=0;j<8;++j){
      const int gn = n0 + (tx<<3) + j;
      if (gn < d.N){
        float x = acc[i][j];
        if (ep==1) x = tanhf(x);
        else if (ep==2){ if (d.bias) x += d.bias[gn]; x = sigmf(x); }
        else if (ep==3){ x += d.bias[gn]; x = DECAY_SCALE * sigmf(x); }
        orow[gn] = x;
      }
    }
  }
}

// ---------------- weight split pre-pass (fp32 -> bf16 hi/lo planes) ----------------
#define NPL (Cc*Cc)
__global__ __launch_bounds__(256) void wsplit_kernel(
    const float* __restrict__ s0, const float* __restrict__ s1,
    const float* __restrict__ s2, const float* __restrict__ s3,
    unsigned short* __restrict__ planes)
{
  const int z = blockIdx.z;
  const float* src = z==0?s0:z==1?s1:z==2?s2:s3;
  unsigned short* dh = planes + (size_t)z*2*NPL;
  unsigned short* dl = dh + NPL;
  const size_t i = ((size_t)blockIdx.x*256 + threadIdx.x)*4;
  float4 v = ld4(src + i);
  const float xs[4] = {v.x, v.y, v.z, v.w};
  unsigned hw[2], lw[2];
  #pragma unroll
  for (int c=0;c<2;++c){
    unsigned u0 = __float_as_uint(xs[2*c]);
    unsigned u1 = __float_as_uint(xs[2*c+1]);
    float l0 = xs[2*c]   - __uint_as_float(u0 & 0xFFFF0000u);
    float l1 = xs[2*c+1] - __uint_as_float(u1 & 0xFFFF0000u);
    hw[c] = (u0>>16) | (u1 & 0xFFFF0000u);
    lw[c] = (__float_as_uint(l0)>>16) | (__float_as_uint(l1) & 0xFFFF0000u);
  }
  uint2 hv; hv.x = hw[0]; hv.y = hw[1];
  uint2 lv; lv.x = lw[0]; lv.y = lw[1];
  *(uint2*)(dh + i) = hv;
  *(uint2*)(dl + i) = lv;
}

// ---------------- split-bf16 MFMA GEMM (big projections) ----------------
// out[m,n] = sum_k A[m,k]*W[n,k]; A fp32 (split in-kernel, truncation),
// W pre-split bf16 hi/lo planes. acc = Ah*Wh + Ah*Wl + Al*Wh (fp32 MFMA acc).
#define TM 128
#define TN 128
#define LDBS 40   // bf16 row stride in LDS

__global__ __launch_bounds__(256) void gemm_mfma(
    GemmDesc d0, GemmDesc d1, GemmDesc d2,
    const unsigned short* __restrict__ WH0, const unsigned short* __restrict__ WL0,
    const unsigned short* __restrict__ WH1, const unsigned short* __restrict__ WL1,
    const unsigned short* __restrict__ WH2, const unsigned short* __restrict__ WL2,
    const float* __restrict__ xmix, const float* __restrict__ hs)
{
  const int z = blockIdx.z;
  GemmDesc d = z==0?d0:(z==1?d1:d2);
  const unsigned short* WH = z==0?WH0:(z==1?WH1:WH2);
  const unsigned short* WL = z==0?WL0:(z==1?WL1:WL2);
  const int m0 = blockIdx.y * TM;
  const int n0 = blockIdx.x * TN;
  const int K  = d.K;
  const int tid = threadIdx.x;

  __shared__ __align__(16) unsigned short Ah[TM*LDBS], Al[TM*LDBS];
  __shared__ __align__(16) unsigned short Bh[TN*LDBS], Bl[TN*LDBS];

  // staging role: row sr (0..127), k-half sk (0/16)
  const int sr = tid >> 1;
  const int sk = (tid & 1) << 4;
  const int gmA = m0 + sr;
  const int gnB = n0 + sr;
  const float* mrow = (d.mixrow >= 0) ? (xmix + (size_t)d.mixrow * Cc) : nullptr;

  float4 pa[4];
  uint4 pwh[2], pwl[2];
  auto load_slab = [&](int kt){
    const int kb = kt*32 + sk;
    #pragma unroll
    for (int u=0;u<4;++u){
      const int kk = kb + 4*u;
      if (mrow){
        float4 h0 = ld4(hs + (size_t)gmA*Cc + kk);
        float4 mx = ld4(mrow + kk);
        float4 hp = make_float4(0.f,0.f,0.f,0.f);
        if ((gmA & (Tt-1)) != 0) hp = ld4(hs + (size_t)(gmA-1)*Cc + kk);
        pa[u].x = h0.x + (hp.x - h0.x)*mx.x;
        pa[u].y = h0.y + (hp.y - h0.y)*mx.y;
        pa[u].z = h0.z + (hp.z - h0.z)*mx.z;
        pa[u].w = h0.w + (hp.w - h0.w)*mx.w;
      } else {
        pa[u] = ld4(d.A + (size_t)gmA*K + kk);
      }
    }
    pwh[0] = *(const uint4*)(WH + (size_t)gnB*K + kb);
    pwh[1] = *(const uint4*)(WH + (size_t)gnB*K + kb + 8);
    pwl[0] = *(const uint4*)(WL + (size_t)gnB*K + kb);
    pwl[1] = *(const uint4*)(WL + (size_t)gnB*K + kb + 8);
  };

  // compute role
  const int wv = tid >> 6, lane = tid & 63;
  const int wm = (wv >> 1) << 6, wn = (wv & 1) << 6;
  const int fr = lane & 15;
  const int fk = (lane >> 4) << 3;

  f32x4 acc[4][4];
  const f32x4 z4 = {0.f,0.f,0.f,0.f};
  #pragma unroll
  for (int i=0;i<4;++i)
    #pragma unroll
    for (int j=0;j<4;++j) acc[i][j]=z4;

  const int nslab = K >> 5;
  load_slab(0);
  for (int kt=0; kt<nslab; ++kt){
    __syncthreads();
    {
      // A split (truncation) + pack
      unsigned hw[8], lw[8];
      #pragma unroll
      for (int u=0;u<4;++u){
        const float xs[4] = {pa[u].x, pa[u].y, pa[u].z, pa[u].w};
        #pragma unroll
        for (int c=0;c<2;++c){
          unsigned u0 = __float_as_uint(xs[2*c]);
          unsigned u1 = __float_as_uint(xs[2*c+1]);
          float l0 = xs[2*c]   - __uint_as_float(u0 & 0xFFFF0000u);
          float l1 = xs[2*c+1] - __uint_as_float(u1 & 0xFFFF0000u);
          hw[u*2+c] = (u0>>16) | (u1 & 0xFFFF0000u);
          lw[u*2+c] = (__float_as_uint(l0)>>16) | (__float_as_uint(l1) & 0xFFFF0000u);
        }
      }
      uint4 t;
      t.x=hw[0];t.y=hw[1];t.z=hw[2];t.w=hw[3]; *(uint4*)&Ah[sr*LDBS+sk]   = t;
      t.x=hw[4];t.y=hw[5];t.z=hw[6];t.w=hw[7]; *(uint4*)&Ah[sr*LDBS+sk+8] = t;
      t.x=lw[0];t.y=lw[1];t.z=lw[2];t.w=lw[3]; *(uint4*)&Al[sr*LDBS+sk]   = t;
      t.x=lw[4];t.y=lw[5];t.z=lw[6];t.w=lw[7]; *(uint4*)&Al[sr*LDBS+sk+8] = t;
      *(uint4*)&Bh[sr*LDBS+sk]   = pwh[0];
      *(uint4*)&Bh[sr*LDBS+sk+8] = pwh[1];
      *(uint4*)&Bl[sr*LDBS+sk]   = pwl[0];
      *(uint4*)&Bl[sr*LDBS+sk+8] = pwl[1];
    }
    __syncthreads();
    if (kt+1 < nslab) load_slab(kt+1);

    short8 bh4[4], bl4[4];
    #pragma unroll
    for (int nt=0;nt<4;++nt){
      bh4[nt] = *(const short8*)&Bh[(wn + nt*16 + fr)*LDBS + fk];
      bl4[nt] = *(const short8*)&Bl[(wn + nt*16 + fr)*LDBS + fk];
    }
    #pragma unroll
    for (int mt=0;mt<4;++mt){
      const short8 ah = *(const short8*)&Ah[(wm + mt*16 + fr)*LDBS + fk];
      const short8 al = *(const short8*)&Al[(wm + mt*16 + fr)*LDBS + fk];
      #pragma unroll
      for (int nt=0;nt<4;++nt)
        acc[mt][nt] = __builtin_amdgcn_mfma_f32_16x16x32_bf16(ah, bh4[nt], acc[mt][nt], 0,0,0);
      #pragma unroll
      for (int nt=0;nt<4;++nt)
        acc[mt][nt] = __builtin_amdgcn_mfma_f32_16x16x32_bf16(ah, bl4[nt], acc[mt][nt], 0,0,0);
      #pragma unroll
      for (int nt=0;nt<4;++nt)
        acc[mt][nt] = __builtin_amdgcn_mfma_f32_16x16x32_bf16(al, bh4[nt], acc[mt][nt], 0,0,0);
    }
  }

  // C/D: col = lane&15 (n), row = (lane>>4)*4 + reg (m)   [m89-verified]
  #pragma unroll
  for (int mt=0;mt<4;++mt){
    #pragma unroll
    for (int nt=0;nt<4;++nt){
      #pragma unroll
      for (int r=0;r<4;++r){
        const int row = wm + mt*16 + ((lane>>4)<<2) + r;
        const int col = wn + nt*16 + fr;
        d.out[(size_t)(m0+row)*d.N + n0 + col] = acc[mt][nt][r];
      }
    }
  }
}

// ---------------- per-head prep (in-place coefficient precompute) ----------------
__global__ __launch_bounds__(256) void head_prep(
    float* kbuf, float* awbuf, float* svwbuf, float* wbbuf, float* vbuf,
    const float* __restrict__ vfirst,
    const float* __restrict__ k_k, const float* __restrict__ k_a)
{
  const int gid = blockIdx.x*4 + (threadIdx.x>>6);
  const int e = threadIdx.x & 63;
  const int m = gid >> 4;
  const int h = gid & 15;
  const int c = h*Dd + e;
  const size_t idx = (size_t)m*Cc + c;
  const float kv0 = kbuf[idx];
  const float av  = awbuf[idx];
  const float sv  = svwbuf[idx];
  const float wv  = wbbuf[idx];
  const float v0  = vbuf[idx];
  const float vf  = vfirst[idx];
  const float kku = kv0 * k_k[c];
  const float ss  = wredsum(kku*kku);
  const float kkn = kku / fmaxf(sqrtf(ss), 1e-12f);
  const float ew  = expf(wv);
  kbuf[idx]  = kv0 * (1.f + (av - 1.f)*k_a[c]);
  awbuf[idx] = ew;
  svwbuf[idx]= -kkn * ew;
  wbbuf[idx] = kkn * av;
  vbuf[idx]  = v0 + sv*(vf - v0);
}

// ---------------- sequential scan v4 ----------------
// 1024 one-wave blocks: 32 col-pair blocks per (b,h) chain -> 4 blocks/CU so
// independent chains interleave per CU (latency hiding). lane = cs*32+rg:
// cs in {0,1} column, rg in 0..31 owns rows 2rg,2rg+1 -> S[2]/lane.
// Per step: 5 x ds_read_b64 (2-way = free) + 1 broadcast + 5+5 shfl.
#define SST4 68   // dword stride per step (68 mod 32 = 4: balanced staging)
__global__ __launch_bounds__(64) void scan_kernel(
    const float* __restrict__ lawb, const float* __restrict__ ewb,
    const float* __restrict__ bbb,  const float* __restrict__ kb,
    const float* __restrict__ rb,   const float* __restrict__ vb,
    float* __restrict__ outp)
{
  const int blk  = blockIdx.x;
  const int bh   = blk & 31;
  const int blkc = blk >> 5;        // 0..31: column pair
  const int b = bh >> 4, h = bh & 15;
  const int lane = threadIdx.x;
  const int cs = lane >> 5;         // 0/1
  const int rg = lane & 31;         // row pair
  const int c0 = blkc * 2;

  __shared__ float Ll[16*SST4], El[16*SST4], Bl[16*SST4], Kl[16*SST4], Rl[16*SST4];
  __shared__ float Vl[32];

  float S0 = 0.f, S1 = 0.f;
  const size_t mbase = (size_t)b*Tt;
  const int g = lane >> 2, q = lane & 3;   // staging: step g, quad q

  float4 pl[4], pe[4], pb4[4], pk[4], pr[4];
  float pv = 0.f;
  auto prefetch = [&](int batch){
    if (batch < Tt/16){
      const size_t m0 = mbase + (size_t)batch*16;
      const size_t rowb = (m0 + g)*Cc + h*Dd;
      #pragma unroll
      for (int u=0;u<4;++u){
        const size_t o = rowb + (q + 4*u)*4;
        pl[u]  = ld4(lawb + o);
        pe[u]  = ld4(ewb  + o);
        pb4[u] = ld4(bbb  + o);
        pk[u]  = ld4(kb   + o);
        pr[u]  = ld4(rb   + o);
      }
      if (lane < 32)
        pv = vb[(m0 + (lane>>1))*Cc + h*Dd + c0 + (lane&1)];
    }
  };
  prefetch(0);

  for (int batch = 0; batch < Tt/16; ++batch){
    __syncthreads();   // previous batch's compute done -> LDS reusable
    #pragma unroll
    for (int u=0;u<4;++u){
      const int ad = g*SST4 + (q + 4*u)*4;
      *(float4*)&Ll[ad] = pl[u];
      *(float4*)&El[ad] = pe[u];
      *(float4*)&Bl[ad] = pb4[u];
      *(float4*)&Kl[ad] = pk[u];
      *(float4*)&Rl[ad] = pr[u];
    }
    if (lane < 32) Vl[lane] = pv;
    __syncthreads();   // staging visible
    prefetch(batch+1); // in flight under this batch's compute

    #pragma unroll 4
    for (int j = 0; j < 16; ++j){
      const float vv = Vl[j*2 + cs];
      const int a0 = j*SST4 + 2*rg;
      const float2 l2 = *(const float2*)&Ll[a0];
      const float2 e2 = *(const float2*)&El[a0];
      float ta = fmaf(l2.y, S1, l2.x*S0);
      S0 *= e2.x; S1 *= e2.y;
      ta += __shfl_xor(ta, 1);
      ta += __shfl_xor(ta, 2);
      ta += __shfl_xor(ta, 4);
      ta += __shfl_xor(ta, 8);
      ta += __shfl_xor(ta, 16);
      const float2 b2 = *(const float2*)&Bl[a0];
      const float2 k2 = *(const float2*)&Kl[a0];
      S0 = fmaf(b2.x, ta, fmaf(k2.x, vv, S0));
      S1 = fmaf(b2.y, ta, fmaf(k2.y, vv, S1));
      const float2 r2 = *(const float2*)&Rl[a0];
      float oe = fmaf(r2.y, S1, r2.x*S0);
      oe += __shfl_xor(oe, 1);
      oe += __shfl_xor(oe, 2);
      oe += __shfl_xor(oe, 4);
      oe += __shfl_xor(oe, 8);
      oe += __shfl_xor(oe, 16);
      if (rg == 0)
        outp[(mbase + (size_t)(batch*16 + j))*Cc + h*Dd + c0 + cs] = oe;
    }
  }
}

// ---------------- GroupNorm + correction + g gating ----------------
__global__ __launch_bounds__(256) void epilogue_kernel(
    const float* __restrict__ att, const float* __restrict__ rbuf,
    const float* __restrict__ kbuf, const float* __restrict__ vbuf,
    const float* __restrict__ gbuf,
    const float* __restrict__ r_k, const float* __restrict__ gn_w,
    const float* __restrict__ gn_b, float* __restrict__ opre)
{
  const int gid = blockIdx.x*4 + (threadIdx.x>>6);
  const int e = threadIdx.x & 63;
  const int m = gid >> 4;
  const int h = gid & 15;
  const int c = h*Dd + e;
  const size_t idx = (size_t)m*Cc + c;
  const float x  = att[idx];
  const float mu = wredsum(x) * (1.f/Dd);
  const float xd = x - mu;
  const float var = wredsum(xd*xd) * (1.f/Dd);
  const float og = xd * (1.f/sqrtf(var + GN_EPS)) * gn_w[c] + gn_b[c];
  const float rv = rbuf[idx], kv = kbuf[idx], vv = vbuf[idx];
  const float cd = wredsum(rv*kv*r_k[c]);
  opre[idx] = (og + cd*vv) * gbuf[idx];
}

extern "C" void kernel_launch(void* const* d_in, const int* in_sizes, int n_in,
                              void* d_out, int out_size, void* d_ws, size_t ws_size,
                              hipStream_t stream)
{
  (void)in_sizes; (void)n_in; (void)out_size; (void)ws_size;
  const float* hs     = (const float*)d_in[0];
  const float* vfirst = (const float*)d_in[1];
  const float* xmix   = (const float*)d_in[2];
  const float* k_k    = (const float*)d_in[3];
  const float* k_a    = (const float*)d_in[4];
  const float* r_k    = (const float*)d_in[5];
  const float* W_r    = (const float*)d_in[6];
  const float* W_k    = (const float*)d_in[7];
  const float* W_v    = (const float*)d_in[8];
  const float* W_o    = (const float*)d_in[9];
  const float* w_A    = (const float*)d_in[10];
  const float* w_B    = (const float*)d_in[11];
  const float* w_b    = (const float*)d_in[12];
  const float* a_A    = (const float*)d_in[13];
  const float* a_B    = (const float*)d_in[14];
  const float* a_b    = (const float*)d_in[15];
  const float* v_A    = (const float*)d_in[16];
  const float* v_B    = (const float*)d_in[17];
  const float* v_b    = (const float*)d_in[18];
  const float* g_A    = (const float*)d_in[19];
  const float* g_B    = (const float*)d_in[20];
  const float* gn_w   = (const float*)d_in[21];
  const float* gn_b   = (const float*)d_in[22];
  float* out = (float*)d_out;
  float* ws  = (float*)d_ws;

  const size_t MC = (size_t)Mm * Cc;
  float* Br   = ws;            // r
  float* Bw   = ws + MC;       // w -> bb (head_prep) -> o_pre (epilogue)
  float* Bk   = ws + 2*MC;     // k0 -> kfin
  float* Bkk  = ws + 3*MC;     // sv -> law
  float* Bv   = ws + 4*MC;     // v0 -> v
  float* Ba   = ws + 5*MC;     // a -> ew
  float* Batt = ws + 6*MC;     // scan output
  float* Bg   = ws + 7*MC;     // g
  float* T1w  = ws + 8*MC;
  float* T1a  = T1w + (size_t)Mm*64;
  float* T1v  = T1a + (size_t)Mm*64;
  float* T1g  = T1v + (size_t)Mm*64;   // Mm*160 floats
  // bf16 weight planes after T1 region: 8 planes x NPL ushorts (16 MB)
  unsigned short* WP = (unsigned short*)(ws + 8*MC + (size_t)Mm*352);
  unsigned short* WrH = WP + 0*(size_t)NPL, *WrL = WP + 1*(size_t)NPL;
  unsigned short* WkH = WP + 2*(size_t)NPL, *WkL = WP + 3*(size_t)NPL;
  unsigned short* WvH = WP + 4*(size_t)NPL, *WvL = WP + 5*(size_t)NPL;
  unsigned short* WoH = WP + 6*(size_t)NPL, *WoL = WP + 7*(size_t)NPL;

  dim3 blk(256,1,1);

  // L0: weight split (W_r, W_k, W_v, W_o -> bf16 hi/lo planes)
  wsplit_kernel<<<dim3(NPL/(256*4),1,4), blk, 0, stream>>>(W_r, W_k, W_v, W_o, WP);

  // L1: big projections r, k0, v0 via split-bf16 MFMA
  GemmDesc dr{nullptr, W_r, Br, nullptr, Cc, Cc, 0, 0};
  GemmDesc dk{nullptr, W_k, Bk, nullptr, Cc, Cc, 2, 0};
  GemmDesc dv{nullptr, W_v, Bv, nullptr, Cc, Cc, 3, 0};
  gemm_mfma<<<dim3(Cc/TN, Mm/TM, 3), blk, 0, stream>>>(
      dr, dk, dv, WrH, WrL, WkH, WkL, WvH, WvL, xmix, hs);

  // L2: LoRA stage-1 (w: tanh; a: none; v: none; g: sigmoid)
  GemmDesc s1w{nullptr, w_A, T1w, nullptr, 64, Cc, 1, 1};
  GemmDesc s1a{nullptr, a_A, T1a, nullptr, 64, Cc, 4, 0};
  GemmDesc s1v{nullptr, v_A, T1v, nullptr, 64, Cc, 3, 0};
  GemmDesc s1g{nullptr, g_A, T1g, nullptr, 160, Cc, 5, 2};
  gemm_kernel<<<dim3(2,32,4), blk, 0, stream>>>(s1w,s1a,s1v,s1g, xmix, hs);

  // L3: LoRA stage-2
  GemmDesc s2w{T1w, w_B, Bw,  w_b,    Cc, 64,  -1, 3};
  GemmDesc s2a{T1a, a_B, Ba,  a_b,    Cc, 64,  -1, 2};
  GemmDesc s2v{T1v, v_B, Bkk, v_b,    Cc, 64,  -1, 2};
  GemmDesc s2g{T1g, g_B, Bg,  nullptr,Cc, 160, -1, 0};
  gemm_kernel<<<dim3(8,32,4), blk, 0, stream>>>(s2w,s2a,s2v,s2g, xmix, hs);

  // L4: per-head prep; in place: Bk k0->kfin, Ba a->ew, Bkk sv->law, Bw w->bb, Bv v0->v
  head_prep<<<dim3(Mm*Hh/4), blk, 0, stream>>>(Bk, Ba, Bkk, Bw, Bv,
                                               vfirst, k_k, k_a);

  // L5: sequential scan (v4: 1024 one-wave blocks, 32 per chain)
  scan_kernel<<<dim3(1024), dim3(64), 0, stream>>>(Bkk, Ba, Bw, Bk, Br, Bv, Batt);

  // L6: groupnorm + corr + g -> o_pre (reuse Bw; bb dead after scan)
  epilogue_kernel<<<dim3(Mm*Hh/4), blk, 0, stream>>>(Batt, Br, Bk, Bv, Bg,
                                                     r_k, gn_w, gn_b, Bw);

  // L7: output projection via split-bf16 MFMA
  GemmDesc doo{Bw, W_o, out, nullptr, Cc, Cc, -1, 0};
  gemm_mfma<<<dim3(Cc/TN, Mm/TM, 1), blk, 0, stream>>>(
      doo, doo, doo, WoH, WoL, WoH, WoL, WoH, WoL, xmix, hs);
}

// Round 5
// 690.683 us; speedup vs baseline: 1.2844x; 1.2844x over previous
//
#include <hip/hip_runtime.h>
#include <math.h>

#define Bb 2
#define Tt 1024
#define Cc 1024
#define Hh 16
#define Dd 64
#define Mm (Bb*Tt)
#define DECAY_SCALE (-0.6065306597126334f)
#define GN_EPS (64e-5f)

typedef __attribute__((ext_vector_type(8))) short short8;   // 8 bf16 (4 VGPRs)
typedef __attribute__((ext_vector_type(4))) float f32x4;    // MFMA acc

struct GemmDesc {
  const float* A;      // used when mixrow < 0 (row stride = K)
  const float* W;      // (N, K) row-major
  float* out;          // (M, N) row-major
  const float* bias;   // per-n bias or nullptr
  int N, K;
  int mixrow;          // >=0: A = token-shift mix of hidden_states with x_mix[mixrow]
  int ep;              // 0 none, 1 tanh, 2 sigmoid(x+bias?), 3 DECAY*sigmoid(x+bias)
};

__device__ __forceinline__ float4 ld4(const float* p){ return *reinterpret_cast<const float4*>(p); }
__device__ __forceinline__ float sigmf(float x){ return 1.f/(1.f+expf(-x)); }

__device__ __forceinline__ float wredsum(float x){
  #pragma unroll
  for (int off=32; off>0; off>>=1) x += __shfl_xor(x, off);
  return x;
}

// 8-lane sum (lanes 8k..8k+7), pure DPP (VALU speed, no LDS pipe):
// xor1 = quad_perm[1,0,3,2]=0xB1; xor2 = quad_perm[2,3,0,1]=0x4E;
// then row_half_mirror (0x141) adds the mirrored quad (== xor4 once quads
// are uniform). Result: full 8-sum in all 8 lanes.
__device__ __forceinline__ float dsum8(float x){
  x += __int_as_float(__builtin_amdgcn_update_dpp(0, __float_as_int(x), 0xB1, 0xF, 0xF, true));
  x += __int_as_float(__builtin_amdgcn_update_dpp(0, __float_as_int(x), 0x4E, 0xF, 0xF, true));
  x += __int_as_float(__builtin_amdgcn_update_dpp(0, __float_as_int(x), 0x141, 0xF, 0xF, true));
  return x;
}

// ---------------- vector-ALU GEMM (LoRA stages only) ----------------
#define BM 64
#define BN 128
#define BK 32

__global__ __launch_bounds__(256) void gemm_kernel(
    GemmDesc d0, GemmDesc d1, GemmDesc d2, GemmDesc d3,
    const float* __restrict__ xmix, const float* __restrict__ hs)
{
  GemmDesc d = (blockIdx.z==0)?d0:(blockIdx.z==1)?d1:(blockIdx.z==2)?d2:d3;
  const int n0 = blockIdx.x * BN;
  if (n0 >= d.N) return;            // block-uniform
  const int m0 = blockIdx.y * BM;
  const int tid = threadIdx.x;
  __shared__ float As[BK][BM+4];
  __shared__ float Bs[BK][BN+4];
  const int ty = tid >> 4, tx = tid & 15;

  float acc[4][8];
  #pragma unroll
  for (int i=0;i<4;++i)
    #pragma unroll
    for (int j=0;j<8;++j) acc[i][j]=0.f;

  const int K = d.K;
  const int nt = K / BK;
  const float* mrow = (d.mixrow >= 0) ? (xmix + (size_t)d.mixrow * Cc) : nullptr;
  float4 pa[2], pb[4];

  auto load_tile = [&](int kt){
    const int kbase = kt * BK;
    #pragma unroll
    for (int u=0;u<2;++u){
      const int li = tid + u*256;
      const int ar = li >> 3;
      const int kk = ((li & 7) << 2) + kbase;
      const int gm = m0 + ar;
      if (mrow){
        float4 h0 = ld4(hs + (size_t)gm*Cc + kk);
        float4 mx = ld4(mrow + kk);
        float4 hp = make_float4(0.f,0.f,0.f,0.f);
        if ((gm & (Tt-1)) != 0) hp = ld4(hs + (size_t)(gm-1)*Cc + kk);
        pa[u].x = h0.x + (hp.x - h0.x)*mx.x;
        pa[u].y = h0.y + (hp.y - h0.y)*mx.y;
        pa[u].z = h0.z + (hp.z - h0.z)*mx.z;
        pa[u].w = h0.w + (hp.w - h0.w)*mx.w;
      } else {
        pa[u] = ld4(d.A + (size_t)gm*K + kk);
      }
    }
    #pragma unroll
    for (int u=0;u<4;++u){
      const int li = tid + u*256;
      const int br = li >> 3;
      const int kk = ((li & 7) << 2) + kbase;
      const int gn = n0 + br;
      pb[u] = (gn < d.N) ? ld4(d.W + (size_t)gn*K + kk) : make_float4(0.f,0.f,0.f,0.f);
    }
  };

  load_tile(0);
  for (int kt=0; kt<nt; ++kt){
    __syncthreads();
    #pragma unroll
    for (int u=0;u<2;++u){
      const int li = tid + u*256;
      const int ar = li >> 3;
      const int kc = (li & 7) << 2;
      As[kc+0][ar] = pa[u].x; As[kc+1][ar] = pa[u].y;
      As[kc+2][ar] = pa[u].z; As[kc+3][ar] = pa[u].w;
    }
    #pragma unroll
    for (int u=0;u<4;++u){
      const int li = tid + u*256;
      const int br = li >> 3;
      const int kc = (li & 7) << 2;
      Bs[kc+0][br] = pb[u].x; Bs[kc+1][br] = pb[u].y;
      Bs[kc+2][br] = pb[u].z; Bs[kc+3][br] = pb[u].w;
    }
    __syncthreads();
    if (kt+1 < nt) load_tile(kt+1);
    #pragma unroll
    for (int kk=0;kk<BK;++kk){
      const float4 a0 = *(const float4*)&As[kk][ty<<2];
      const float4 b0 = *(const float4*)&Bs[kk][tx<<3];
      const float4 b1 = *(const float4*)&Bs[kk][(tx<<3)+4];
      const float av[4] = {a0.x,a0.y,a0.z,a0.w};
      const float bv[8] = {b0.x,b0.y,b0.z,b0.w,b1.x,b1.y,b1.z,b1.w};
      #pragma unroll
      for (int i=0;i<4;++i)
        #pragma unroll
        for (int j=0;j<8;++j)
          acc[i][j] = fmaf(av[i], bv[j], acc[i][j]);
    }
  }

  const int ep = d.ep;
  #pragma unroll
  for (int i=0;i<4;++i){
    const int gm = m0 + (ty<<2) + i;
    float* orow = d.out + (size_t)gm * d.N;
    #pragma unroll
    for (int j=0;j<8;++j){
      const int gn = n0 + (tx<<3) + j;
      if (gn < d.N){
        float x = acc[i][j];
        if (ep==1) x = tanhf(x);
        else if (ep==2){ if (d.bias) x += d.bias[gn]; x = sigmf(x); }
        else if (ep==3){ x += d.bias[gn]; x = DECAY_SCALE * sigmf(x); }
        orow[gn] = x;
      }
    }
  }
}

// ---------------- weight split pre-pass (fp32 -> bf16 hi/lo planes) ----------------
#define NPL (Cc*Cc)
__global__ __launch_bounds__(256) void wsplit_kernel(
    const float* __restrict__ s0, const float* __restrict__ s1,
    const float* __restrict__ s2, const float* __restrict__ s3,
    unsigned short* __restrict__ planes)
{
  const int z = blockIdx.z;
  const float* src = z==0?s0:z==1?s1:z==2?s2:s3;
  unsigned short* dh = planes + (size_t)z*2*NPL;
  unsigned short* dl = dh + NPL;
  const size_t i = ((size_t)blockIdx.x*256 + threadIdx.x)*4;
  float4 v = ld4(src + i);
  const float xs[4] = {v.x, v.y, v.z, v.w};
  unsigned hw[2], lw[2];
  #pragma unroll
  for (int c=0;c<2;++c){
    unsigned u0 = __float_as_uint(xs[2*c]);
    unsigned u1 = __float_as_uint(xs[2*c+1]);
    float l0 = xs[2*c]   - __uint_as_float(u0 & 0xFFFF0000u);
    float l1 = xs[2*c+1] - __uint_as_float(u1 & 0xFFFF0000u);
    hw[c] = (u0>>16) | (u1 & 0xFFFF0000u);
    lw[c] = (__float_as_uint(l0)>>16) | (__float_as_uint(l1) & 0xFFFF0000u);
  }
  uint2 hv; hv.x = hw[0]; hv.y = hw[1];
  uint2 lv; lv.x = lw[0]; lv.y = lw[1];
  *(uint2*)(dh + i) = hv;
  *(uint2*)(dl + i) = lv;
}

// ---------------- split-bf16 MFMA GEMM (big projections) ----------------
#define TM 128
#define TN 128
#define LDBS 40   // bf16 row stride in LDS

__global__ __launch_bounds__(256) void gemm_mfma(
    GemmDesc d0, GemmDesc d1, GemmDesc d2,
    const unsigned short* __restrict__ WH0, const unsigned short* __restrict__ WL0,
    const unsigned short* __restrict__ WH1, const unsigned short* __restrict__ WL1,
    const unsigned short* __restrict__ WH2, const unsigned short* __restrict__ WL2,
    const float* __restrict__ xmix, const float* __restrict__ hs)
{
  const int z = blockIdx.z;
  GemmDesc d = z==0?d0:(z==1?d1:d2);
  const unsigned short* WH = z==0?WH0:(z==1?WH1:WH2);
  const unsigned short* WL = z==0?WL0:(z==1?WL1:WL2);
  const int m0 = blockIdx.y * TM;
  const int n0 = blockIdx.x * TN;
  const int K  = d.K;
  const int tid = threadIdx.x;

  __shared__ __align__(16) unsigned short Ah[TM*LDBS], Al[TM*LDBS];
  __shared__ __align__(16) unsigned short Bh[TN*LDBS], Bl[TN*LDBS];

  const int sr = tid >> 1;
  const int sk = (tid & 1) << 4;
  const int gmA = m0 + sr;
  const int gnB = n0 + sr;
  const float* mrow = (d.mixrow >= 0) ? (xmix + (size_t)d.mixrow * Cc) : nullptr;

  float4 pa[4];
  uint4 pwh[2], pwl[2];
  auto load_slab = [&](int kt){
    const int kb = kt*32 + sk;
    #pragma unroll
    for (int u=0;u<4;++u){
      const int kk = kb + 4*u;
      if (mrow){
        float4 h0 = ld4(hs + (size_t)gmA*Cc + kk);
        float4 mx = ld4(mrow + kk);
        float4 hp = make_float4(0.f,0.f,0.f,0.f);
        if ((gmA & (Tt-1)) != 0) hp = ld4(hs + (size_t)(gmA-1)*Cc + kk);
        pa[u].x = h0.x + (hp.x - h0.x)*mx.x;
        pa[u].y = h0.y + (hp.y - h0.y)*mx.y;
        pa[u].z = h0.z + (hp.z - h0.z)*mx.z;
        pa[u].w = h0.w + (hp.w - h0.w)*mx.w;
      } else {
        pa[u] = ld4(d.A + (size_t)gmA*K + kk);
      }
    }
    pwh[0] = *(const uint4*)(WH + (size_t)gnB*K + kb);
    pwh[1] = *(const uint4*)(WH + (size_t)gnB*K + kb + 8);
    pwl[0] = *(const uint4*)(WL + (size_t)gnB*K + kb);
    pwl[1] = *(const uint4*)(WL + (size_t)gnB*K + kb + 8);
  };

  const int wv = tid >> 6, lane = tid & 63;
  const int wm = (wv >> 1) << 6, wn = (wv & 1) << 6;
  const int fr = lane & 15;
  const int fk = (lane >> 4) << 3;

  f32x4 acc[4][4];
  const f32x4 z4 = {0.f,0.f,0.f,0.f};
  #pragma unroll
  for (int i=0;i<4;++i)
    #pragma unroll
    for (int j=0;j<4;++j) acc[i][j]=z4;

  const int nslab = K >> 5;
  load_slab(0);
  for (int kt=0; kt<nslab; ++kt){
    __syncthreads();
    {
      unsigned hw[8], lw[8];
      #pragma unroll
      for (int u=0;u<4;++u){
        const float xs[4] = {pa[u].x, pa[u].y, pa[u].z, pa[u].w};
        #pragma unroll
        for (int c=0;c<2;++c){
          unsigned u0 = __float_as_uint(xs[2*c]);
          unsigned u1 = __float_as_uint(xs[2*c+1]);
          float l0 = xs[2*c]   - __uint_as_float(u0 & 0xFFFF0000u);
          float l1 = xs[2*c+1] - __uint_as_float(u1 & 0xFFFF0000u);
          hw[u*2+c] = (u0>>16) | (u1 & 0xFFFF0000u);
          lw[u*2+c] = (__float_as_uint(l0)>>16) | (__float_as_uint(l1) & 0xFFFF0000u);
        }
      }
      uint4 t;
      t.x=hw[0];t.y=hw[1];t.z=hw[2];t.w=hw[3]; *(uint4*)&Ah[sr*LDBS+sk]   = t;
      t.x=hw[4];t.y=hw[5];t.z=hw[6];t.w=hw[7]; *(uint4*)&Ah[sr*LDBS+sk+8] = t;
      t.x=lw[0];t.y=lw[1];t.z=lw[2];t.w=lw[3]; *(uint4*)&Al[sr*LDBS+sk]   = t;
      t.x=lw[4];t.y=lw[5];t.z=lw[6];t.w=lw[7]; *(uint4*)&Al[sr*LDBS+sk+8] = t;
      *(uint4*)&Bh[sr*LDBS+sk]   = pwh[0];
      *(uint4*)&Bh[sr*LDBS+sk+8] = pwh[1];
      *(uint4*)&Bl[sr*LDBS+sk]   = pwl[0];
      *(uint4*)&Bl[sr*LDBS+sk+8] = pwl[1];
    }
    __syncthreads();
    if (kt+1 < nslab) load_slab(kt+1);

    short8 bh4[4], bl4[4];
    #pragma unroll
    for (int nt=0;nt<4;++nt){
      bh4[nt] = *(const short8*)&Bh[(wn + nt*16 + fr)*LDBS + fk];
      bl4[nt] = *(const short8*)&Bl[(wn + nt*16 + fr)*LDBS + fk];
    }
    #pragma unroll
    for (int mt=0;mt<4;++mt){
      const short8 ah = *(const short8*)&Ah[(wm + mt*16 + fr)*LDBS + fk];
      const short8 al = *(const short8*)&Al[(wm + mt*16 + fr)*LDBS + fk];
      #pragma unroll
      for (int nt=0;nt<4;++nt)
        acc[mt][nt] = __builtin_amdgcn_mfma_f32_16x16x32_bf16(ah, bh4[nt], acc[mt][nt], 0,0,0);
      #pragma unroll
      for (int nt=0;nt<4;++nt)
        acc[mt][nt] = __builtin_amdgcn_mfma_f32_16x16x32_bf16(ah, bl4[nt], acc[mt][nt], 0,0,0);
      #pragma unroll
      for (int nt=0;nt<4;++nt)
        acc[mt][nt] = __builtin_amdgcn_mfma_f32_16x16x32_bf16(al, bh4[nt], acc[mt][nt], 0,0,0);
    }
  }

  #pragma unroll
  for (int mt=0;mt<4;++mt){
    #pragma unroll
    for (int nt=0;nt<4;++nt){
      #pragma unroll
      for (int r=0;r<4;++r){
        const int row = wm + mt*16 + ((lane>>4)<<2) + r;
        const int col = wn + nt*16 + fr;
        d.out[(size_t)(m0+row)*d.N + n0 + col] = acc[mt][nt][r];
      }
    }
  }
}

// ---------------- per-head prep (in-place coefficient precompute) ----------------
__global__ __launch_bounds__(256) void head_prep(
    float* kbuf, float* awbuf, float* svwbuf, float* wbbuf, float* vbuf,
    const float* __restrict__ vfirst,
    const float* __restrict__ k_k, const float* __restrict__ k_a)
{
  const int gid = blockIdx.x*4 + (threadIdx.x>>6);
  const int e = threadIdx.x & 63;
  const int m = gid >> 4;
  const int h = gid & 15;
  const int c = h*Dd + e;
  const size_t idx = (size_t)m*Cc + c;
  const float kv0 = kbuf[idx];
  const float av  = awbuf[idx];
  const float sv  = svwbuf[idx];
  const float wv  = wbbuf[idx];
  const float v0  = vbuf[idx];
  const float vf  = vfirst[idx];
  const float kku = kv0 * k_k[c];
  const float ss  = wredsum(kku*kku);
  const float kkn = kku / fmaxf(sqrtf(ss), 1e-12f);
  const float ew  = expf(wv);
  kbuf[idx]  = kv0 * (1.f + (av - 1.f)*k_a[c]);
  awbuf[idx] = ew;
  svwbuf[idx]= -kkn * ew;
  wbbuf[idx] = kkn * av;
  vbuf[idx]  = v0 + sv*(vf - v0);
}

// ---------------- sequential scan v5: DPP reductions ----------------
// 256 one-wave blocks, 8 per (b,h) chain (block owns 8 columns). lane =
// es*8+rq: es = column slot (0..7), rq = row octet (d in [8rq,8rq+8)), so the
// reduction group is 8 CONSECUTIVE lanes -> dsum8 is pure DPP (no LDS pipe,
// ~12 cyc vs ~600 for serial ds_bpermute chains in v3/v4).
// Coefficients interleaved (law,ew,bb,k) float4 per (t,d) in skewed LDS:
// 8 conflict-free b128 reads + 2 r-reads + 1 v-read per step, all pipelined.
#define C4ST 292   // dword stride per step of C4 block (292%32=4 -> skewed)
#define RST  100   // dword stride per step of R block (12/octet skew)
__global__ __launch_bounds__(64) void scan_kernel(
    const float* __restrict__ lawb, const float* __restrict__ ewb,
    const float* __restrict__ bbb,  const float* __restrict__ kb,
    const float* __restrict__ rb,   const float* __restrict__ vb,
    float* __restrict__ outp)
{
  const int blk  = blockIdx.x;
  const int bh   = blk & 31;        // chain's 8 blocks %32-congruent -> same XCD
  const int blkc = blk >> 5;        // 0..7: column octet
  const int b = bh >> 4, h = bh & 15;
  const int lane = threadIdx.x;
  const int es = lane >> 3;         // column slot 0..7
  const int rq = lane & 7;          // row octet
  const int c0 = blkc * 8;
  const int hb = h * Dd;

  __shared__ float C4L[16*C4ST];    // (law,ew,bb,k) per (t,d)
  __shared__ float RL[16*RST];      // r per (t,d)
  __shared__ float VL[16*8];        // v per (t, block column)

  float S[8];
  #pragma unroll
  for (int j=0;j<8;++j) S[j]=0.f;

  const size_t mbase = (size_t)b*Tt;
  const int g = lane >> 2, q = lane & 3;   // staging: step g, quad q

  float4 pl[4], pe[4], pb4[4], pk[4], pr[4];
  float2 pv;
  auto prefetch = [&](int batch){
    if (batch < Tt/16){
      const size_t rowb = (mbase + (size_t)batch*16 + g)*Cc + hb;
      #pragma unroll
      for (int u=0;u<4;++u){
        const int d0 = 4*q + 16*u;
        pl[u]  = ld4(lawb + rowb + d0);
        pe[u]  = ld4(ewb  + rowb + d0);
        pb4[u] = ld4(bbb  + rowb + d0);
        pk[u]  = ld4(kb   + rowb + d0);
        pr[u]  = ld4(rb   + rowb + d0);
      }
      pv = *(const float2*)(vb + rowb + c0 + 2*q);
    }
  };
  prefetch(0);

  for (int batch = 0; batch < Tt/16; ++batch){
    __syncthreads();   // previous batch's compute done -> LDS reusable
    #pragma unroll
    for (int u=0;u<4;++u){
      const int d0 = 4*q + 16*u;
      const float lw[4] = {pl[u].x,  pl[u].y,  pl[u].z,  pl[u].w};
      const float ew[4] = {pe[u].x,  pe[u].y,  pe[u].z,  pe[u].w};
      const float bw[4] = {pb4[u].x, pb4[u].y, pb4[u].z, pb4[u].w};
      const float kw[4] = {pk[u].x,  pk[u].y,  pk[u].z,  pk[u].w};
      #pragma unroll
      for (int jj=0;jj<4;++jj){
        const int dg = d0 + jj;
        const int ad = g*C4ST + (dg>>3)*36 + (dg&7)*4;
        *(float4*)&C4L[ad] = make_float4(lw[jj], ew[jj], bw[jj], kw[jj]);
      }
      *(float4*)&RL[g*RST + (d0>>3)*12 + (d0&7)] = pr[u];
    }
    *(float2*)&VL[g*8 + 2*q] = pv;
    __syncthreads();   // staging visible
    prefetch(batch+1); // in flight under this batch's compute

    const int cbase = rq*36;
    const int rbase = rq*12;
    #pragma unroll 4
    for (int j = 0; j < 16; ++j){
      float4 c[8];
      const int cb = j*C4ST + cbase;
      #pragma unroll
      for (int p=0;p<8;++p) c[p] = *(const float4*)&C4L[cb + 4*p];
      const float vv = VL[j*8 + es];
      float ta = 0.f, tb = 0.f;
      ta = fmaf(c[0].x, S[0], ta); tb = fmaf(c[1].x, S[1], tb);
      ta = fmaf(c[2].x, S[2], ta); tb = fmaf(c[3].x, S[3], tb);
      ta = fmaf(c[4].x, S[4], ta); tb = fmaf(c[5].x, S[5], tb);
      ta = fmaf(c[6].x, S[6], ta); tb = fmaf(c[7].x, S[7], tb);
      ta = dsum8(ta + tb);
      #pragma unroll
      for (int p=0;p<8;++p)
        S[p] = fmaf(c[p].y, S[p], fmaf(c[p].z, ta, c[p].w*vv));
      const float4 r0 = *(const float4*)&RL[j*RST + rbase];
      const float4 r1 = *(const float4*)&RL[j*RST + rbase + 4];
      float oe = 0.f, ob = 0.f;
      oe = fmaf(r0.x, S[0], oe); ob = fmaf(r0.y, S[1], ob);
      oe = fmaf(r0.z, S[2], oe); ob = fmaf(r0.w, S[3], ob);
      oe = fmaf(r1.x, S[4], oe); ob = fmaf(r1.y, S[5], ob);
      oe = fmaf(r1.z, S[6], oe); ob = fmaf(r1.w, S[7], ob);
      oe = dsum8(oe + ob);
      if (rq == 0)
        outp[(mbase + (size_t)(batch*16 + j))*Cc + hb + c0 + es] = oe;
    }
  }
}

// ---------------- GroupNorm + correction + g gating ----------------
__global__ __launch_bounds__(256) void epilogue_kernel(
    const float* __restrict__ att, const float* __restrict__ rbuf,
    const float* __restrict__ kbuf, const float* __restrict__ vbuf,
    const float* __restrict__ gbuf,
    const float* __restrict__ r_k, const float* __restrict__ gn_w,
    const float* __restrict__ gn_b, float* __restrict__ opre)
{
  const int gid = blockIdx.x*4 + (threadIdx.x>>6);
  const int e = threadIdx.x & 63;
  const int m = gid >> 4;
  const int h = gid & 15;
  const int c = h*Dd + e;
  const size_t idx = (size_t)m*Cc + c;
  const float x  = att[idx];
  const float mu = wredsum(x) * (1.f/Dd);
  const float xd = x - mu;
  const float var = wredsum(xd*xd) * (1.f/Dd);
  const float og = xd * (1.f/sqrtf(var + GN_EPS)) * gn_w[c] + gn_b[c];
  const float rv = rbuf[idx], kv = kbuf[idx], vv = vbuf[idx];
  const float cd = wredsum(rv*kv*r_k[c]);
  opre[idx] = (og + cd*vv) * gbuf[idx];
}

extern "C" void kernel_launch(void* const* d_in, const int* in_sizes, int n_in,
                              void* d_out, int out_size, void* d_ws, size_t ws_size,
                              hipStream_t stream)
{
  (void)in_sizes; (void)n_in; (void)out_size; (void)ws_size;
  const float* hs     = (const float*)d_in[0];
  const float* vfirst = (const float*)d_in[1];
  const float* xmix   = (const float*)d_in[2];
  const float* k_k    = (const float*)d_in[3];
  const float* k_a    = (const float*)d_in[4];
  const float* r_k    = (const float*)d_in[5];
  const float* W_r    = (const float*)d_in[6];
  const float* W_k    = (const float*)d_in[7];
  const float* W_v    = (const float*)d_in[8];
  const float* W_o    = (const float*)d_in[9];
  const float* w_A    = (const float*)d_in[10];
  const float* w_B    = (const float*)d_in[11];
  const float* w_b    = (const float*)d_in[12];
  const float* a_A    = (const float*)d_in[13];
  const float* a_B    = (const float*)d_in[14];
  const float* a_b    = (const float*)d_in[15];
  const float* v_A    = (const float*)d_in[16];
  const float* v_B    = (const float*)d_in[17];
  const float* v_b    = (const float*)d_in[18];
  const float* g_A    = (const float*)d_in[19];
  const float* g_B    = (const float*)d_in[20];
  const float* gn_w   = (const float*)d_in[21];
  const float* gn_b   = (const float*)d_in[22];
  float* out = (float*)d_out;
  float* ws  = (float*)d_ws;

  const size_t MC = (size_t)Mm * Cc;
  float* Br   = ws;            // r
  float* Bw   = ws + MC;       // w -> bb (head_prep) -> o_pre (epilogue)
  float* Bk   = ws + 2*MC;     // k0 -> kfin
  float* Bkk  = ws + 3*MC;     // sv -> law
  float* Bv   = ws + 4*MC;     // v0 -> v
  float* Ba   = ws + 5*MC;     // a -> ew
  float* Batt = ws + 6*MC;     // scan output
  float* Bg   = ws + 7*MC;     // g
  float* T1w  = ws + 8*MC;
  float* T1a  = T1w + (size_t)Mm*64;
  float* T1v  = T1a + (size_t)Mm*64;
  float* T1g  = T1v + (size_t)Mm*64;   // Mm*160 floats
  unsigned short* WP = (unsigned short*)(ws + 8*MC + (size_t)Mm*352);
  unsigned short* WrH = WP + 0*(size_t)NPL, *WrL = WP + 1*(size_t)NPL;
  unsigned short* WkH = WP + 2*(size_t)NPL, *WkL = WP + 3*(size_t)NPL;
  unsigned short* WvH = WP + 4*(size_t)NPL, *WvL = WP + 5*(size_t)NPL;
  unsigned short* WoH = WP + 6*(size_t)NPL, *WoL = WP + 7*(size_t)NPL;

  dim3 blk(256,1,1);

  // L0: weight split (W_r, W_k, W_v, W_o -> bf16 hi/lo planes)
  wsplit_kernel<<<dim3(NPL/(256*4),1,4), blk, 0, stream>>>(W_r, W_k, W_v, W_o, WP);

  // L1: big projections r, k0, v0 via split-bf16 MFMA
  GemmDesc dr{nullptr, W_r, Br, nullptr, Cc, Cc, 0, 0};
  GemmDesc dk{nullptr, W_k, Bk, nullptr, Cc, Cc, 2, 0};
  GemmDesc dv{nullptr, W_v, Bv, nullptr, Cc, Cc, 3, 0};
  gemm_mfma<<<dim3(Cc/TN, Mm/TM, 3), blk, 0, stream>>>(
      dr, dk, dv, WrH, WrL, WkH, WkL, WvH, WvL, xmix, hs);

  // L2: LoRA stage-1 (w: tanh; a: none; v: none; g: sigmoid)
  GemmDesc s1w{nullptr, w_A, T1w, nullptr, 64, Cc, 1, 1};
  GemmDesc s1a{nullptr, a_A, T1a, nullptr, 64, Cc, 4, 0};
  GemmDesc s1v{nullptr, v_A, T1v, nullptr, 64, Cc, 3, 0};
  GemmDesc s1g{nullptr, g_A, T1g, nullptr, 160, Cc, 5, 2};
  gemm_kernel<<<dim3(2,32,4), blk, 0, stream>>>(s1w,s1a,s1v,s1g, xmix, hs);

  // L3: LoRA stage-2
  GemmDesc s2w{T1w, w_B, Bw,  w_b,    Cc, 64,  -1, 3};
  GemmDesc s2a{T1a, a_B, Ba,  a_b,    Cc, 64,  -1, 2};
  GemmDesc s2v{T1v, v_B, Bkk, v_b,    Cc, 64,  -1, 2};
  GemmDesc s2g{T1g, g_B, Bg,  nullptr,Cc, 160, -1, 0};
  gemm_kernel<<<dim3(8,32,4), blk, 0, stream>>>(s2w,s2a,s2v,s2g, xmix, hs);

  // L4: per-head prep; in place: Bk k0->kfin, Ba a->ew, Bkk sv->law, Bw w->bb, Bv v0->v
  head_prep<<<dim3(Mm*Hh/4), blk, 0, stream>>>(Bk, Ba, Bkk, Bw, Bv,
                                               vfirst, k_k, k_a);

  // L5: sequential scan (v5: 256 one-wave blocks, DPP reductions)
  scan_kernel<<<dim3(256), dim3(64), 0, stream>>>(Bkk, Ba, Bw, Bk, Br, Bv, Batt);

  // L6: groupnorm + corr + g -> o_pre (reuse Bw; bb dead after scan)
  epilogue_kernel<<<dim3(Mm*Hh/4), blk, 0, stream>>>(Batt, Br, Bk, Bv, Bg,
                                                     r_k, gn_w, gn_b, Bw);

  // L7: output projection via split-bf16 MFMA
  GemmDesc doo{Bw, W_o, out, nullptr, Cc, Cc, -1, 0};
  gemm_mfma<<<dim3(Cc/TN, Mm/TM, 1), blk, 0, stream>>>(
      doo, doo, doo, WoH, WoL, WoH, WoL, WoH, WoL, xmix, hs);
}

// Round 6
// 687.695 us; speedup vs baseline: 1.2900x; 1.0043x over previous
//
#include <hip/hip_runtime.h>
#include <math.h>

#define Bb 2
#define Tt 1024
#define Cc 1024
#define Hh 16
#define Dd 64
#define Mm (Bb*Tt)
#define DECAY_SCALE (-0.6065306597126334f)
#define GN_EPS (64e-5f)

typedef __attribute__((ext_vector_type(8))) short short8;   // 8 bf16 (4 VGPRs)
typedef __attribute__((ext_vector_type(4))) float f32x4;    // MFMA acc

struct GemmDesc {
  const float* A;      // used when mixrow < 0 (row stride = K)
  const float* W;      // (N, K) row-major
  float* out;          // (M, N) row-major
  const float* bias;   // per-n bias or nullptr
  int N, K;
  int mixrow;          // >=0: A = token-shift mix of hidden_states with x_mix[mixrow]
  int ep;              // 0 none, 1 tanh, 2 sigmoid(x+bias?), 3 DECAY*sigmoid(x+bias)
};

__device__ __forceinline__ float4 ld4(const float* p){ return *reinterpret_cast<const float4*>(p); }
__device__ __forceinline__ float sigmf(float x){ return 1.f/(1.f+expf(-x)); }

__device__ __forceinline__ float wredsum(float x){
  #pragma unroll
  for (int off=32; off>0; off>>=1) x += __shfl_xor(x, off);
  return x;
}

// 16-lane sum (lanes 16k..16k+15), pure DPP (VALU speed, no LDS pipe):
// xor1 = quad_perm 0xB1; xor2 = quad_perm 0x4E; half_mirror 0x141 (==xor4 once
// quads uniform); row_mirror 0x140 (==xor8 once octets uniform).
__device__ __forceinline__ float dsum16(float x){
  x += __int_as_float(__builtin_amdgcn_update_dpp(0, __float_as_int(x), 0xB1, 0xF, 0xF, true));
  x += __int_as_float(__builtin_amdgcn_update_dpp(0, __float_as_int(x), 0x4E, 0xF, 0xF, true));
  x += __int_as_float(__builtin_amdgcn_update_dpp(0, __float_as_int(x), 0x141, 0xF, 0xF, true));
  x += __int_as_float(__builtin_amdgcn_update_dpp(0, __float_as_int(x), 0x140, 0xF, 0xF, true));
  return x;
}

// ---------------- vector-ALU GEMM (LoRA stages only) ----------------
#define BM 64
#define BN 128
#define BK 32

__global__ __launch_bounds__(256) void gemm_kernel(
    GemmDesc d0, GemmDesc d1, GemmDesc d2, GemmDesc d3,
    const float* __restrict__ xmix, const float* __restrict__ hs)
{
  GemmDesc d = (blockIdx.z==0)?d0:(blockIdx.z==1)?d1:(blockIdx.z==2)?d2:d3;
  const int n0 = blockIdx.x * BN;
  if (n0 >= d.N) return;            // block-uniform
  const int m0 = blockIdx.y * BM;
  const int tid = threadIdx.x;
  __shared__ float As[BK][BM+4];
  __shared__ float Bs[BK][BN+4];
  const int ty = tid >> 4, tx = tid & 15;

  float acc[4][8];
  #pragma unroll
  for (int i=0;i<4;++i)
    #pragma unroll
    for (int j=0;j<8;++j) acc[i][j]=0.f;

  const int K = d.K;
  const int nt = K / BK;
  const float* mrow = (d.mixrow >= 0) ? (xmix + (size_t)d.mixrow * Cc) : nullptr;
  float4 pa[2], pb[4];

  auto load_tile = [&](int kt){
    const int kbase = kt * BK;
    #pragma unroll
    for (int u=0;u<2;++u){
      const int li = tid + u*256;
      const int ar = li >> 3;
      const int kk = ((li & 7) << 2) + kbase;
      const int gm = m0 + ar;
      if (mrow){
        float4 h0 = ld4(hs + (size_t)gm*Cc + kk);
        float4 mx = ld4(mrow + kk);
        float4 hp = make_float4(0.f,0.f,0.f,0.f);
        if ((gm & (Tt-1)) != 0) hp = ld4(hs + (size_t)(gm-1)*Cc + kk);
        pa[u].x = h0.x + (hp.x - h0.x)*mx.x;
        pa[u].y = h0.y + (hp.y - h0.y)*mx.y;
        pa[u].z = h0.z + (hp.z - h0.z)*mx.z;
        pa[u].w = h0.w + (hp.w - h0.w)*mx.w;
      } else {
        pa[u] = ld4(d.A + (size_t)gm*K + kk);
      }
    }
    #pragma unroll
    for (int u=0;u<4;++u){
      const int li = tid + u*256;
      const int br = li >> 3;
      const int kk = ((li & 7) << 2) + kbase;
      const int gn = n0 + br;
      pb[u] = (gn < d.N) ? ld4(d.W + (size_t)gn*K + kk) : make_float4(0.f,0.f,0.f,0.f);
    }
  };

  load_tile(0);
  for (int kt=0; kt<nt; ++kt){
    __syncthreads();
    #pragma unroll
    for (int u=0;u<2;++u){
      const int li = tid + u*256;
      const int ar = li >> 3;
      const int kc = (li & 7) << 2;
      As[kc+0][ar] = pa[u].x; As[kc+1][ar] = pa[u].y;
      As[kc+2][ar] = pa[u].z; As[kc+3][ar] = pa[u].w;
    }
    #pragma unroll
    for (int u=0;u<4;++u){
      const int li = tid + u*256;
      const int br = li >> 3;
      const int kc = (li & 7) << 2;
      Bs[kc+0][br] = pb[u].x; Bs[kc+1][br] = pb[u].y;
      Bs[kc+2][br] = pb[u].z; Bs[kc+3][br] = pb[u].w;
    }
    __syncthreads();
    if (kt+1 < nt) load_tile(kt+1);
    #pragma unroll
    for (int kk=0;kk<BK;++kk){
      const float4 a0 = *(const float4*)&As[kk][ty<<2];
      const float4 b0 = *(const float4*)&Bs[kk][tx<<3];
      const float4 b1 = *(const float4*)&Bs[kk][(tx<<3)+4];
      const float av[4] = {a0.x,a0.y,a0.z,a0.w};
      const float bv[8] = {b0.x,b0.y,b0.z,b0.w,b1.x,b1.y,b1.z,b1.w};
      #pragma unroll
      for (int i=0;i<4;++i)
        #pragma unroll
        for (int j=0;j<8;++j)
          acc[i][j] = fmaf(av[i], bv[j], acc[i][j]);
    }
  }

  const int ep = d.ep;
  #pragma unroll
  for (int i=0;i<4;++i){
    const int gm = m0 + (ty<<2) + i;
    float* orow = d.out + (size_t)gm * d.N;
    #pragma unroll
    for (int j=0;j<8;++j){
      const int gn = n0 + (tx<<3) + j;
      if (gn < d.N){
        float x = acc[i][j];
        if (ep==1) x = tanhf(x);
        else if (ep==2){ if (d.bias) x += d.bias[gn]; x = sigmf(x); }
        else if (ep==3){ x += d.bias[gn]; x = DECAY_SCALE * sigmf(x); }
        orow[gn] = x;
      }
    }
  }
}

// ---------------- weight split pre-pass (fp32 -> bf16 hi/lo planes) ----------------
#define NPL (Cc*Cc)
__global__ __launch_bounds__(256) void wsplit_kernel(
    const float* __restrict__ s0, const float* __restrict__ s1,
    const float* __restrict__ s2, const float* __restrict__ s3,
    unsigned short* __restrict__ planes)
{
  const int z = blockIdx.z;
  const float* src = z==0?s0:z==1?s1:z==2?s2:s3;
  unsigned short* dh = planes + (size_t)z*2*NPL;
  unsigned short* dl = dh + NPL;
  const size_t i = ((size_t)blockIdx.x*256 + threadIdx.x)*4;
  float4 v = ld4(src + i);
  const float xs[4] = {v.x, v.y, v.z, v.w};
  unsigned hw[2], lw[2];
  #pragma unroll
  for (int c=0;c<2;++c){
    unsigned u0 = __float_as_uint(xs[2*c]);
    unsigned u1 = __float_as_uint(xs[2*c+1]);
    float l0 = xs[2*c]   - __uint_as_float(u0 & 0xFFFF0000u);
    float l1 = xs[2*c+1] - __uint_as_float(u1 & 0xFFFF0000u);
    hw[c] = (u0>>16) | (u1 & 0xFFFF0000u);
    lw[c] = (__float_as_uint(l0)>>16) | (__float_as_uint(l1) & 0xFFFF0000u);
  }
  uint2 hv; hv.x = hw[0]; hv.y = hw[1];
  uint2 lv; lv.x = lw[0]; lv.y = lw[1];
  *(uint2*)(dh + i) = hv;
  *(uint2*)(dl + i) = lv;
}

// ---------------- split-bf16 MFMA GEMM (big projections) ----------------
#define TM 128
#define TN 128
#define LDBS 40   // bf16 row stride in LDS

__global__ __launch_bounds__(256) void gemm_mfma(
    GemmDesc d0, GemmDesc d1, GemmDesc d2,
    const unsigned short* __restrict__ WH0, const unsigned short* __restrict__ WL0,
    const unsigned short* __restrict__ WH1, const unsigned short* __restrict__ WL1,
    const unsigned short* __restrict__ WH2, const unsigned short* __restrict__ WL2,
    const float* __restrict__ xmix, const float* __restrict__ hs)
{
  const int z = blockIdx.z;
  GemmDesc d = z==0?d0:(z==1?d1:d2);
  const unsigned short* WH = z==0?WH0:(z==1?WH1:WH2);
  const unsigned short* WL = z==0?WL0:(z==1?WL1:WL2);
  const int m0 = blockIdx.y * TM;
  const int n0 = blockIdx.x * TN;
  const int K  = d.K;
  const int tid = threadIdx.x;

  __shared__ __align__(16) unsigned short Ah[TM*LDBS], Al[TM*LDBS];
  __shared__ __align__(16) unsigned short Bh[TN*LDBS], Bl[TN*LDBS];

  const int sr = tid >> 1;
  const int sk = (tid & 1) << 4;
  const int gmA = m0 + sr;
  const int gnB = n0 + sr;
  const float* mrow = (d.mixrow >= 0) ? (xmix + (size_t)d.mixrow * Cc) : nullptr;

  float4 pa[4];
  uint4 pwh[2], pwl[2];
  auto load_slab = [&](int kt){
    const int kb = kt*32 + sk;
    #pragma unroll
    for (int u=0;u<4;++u){
      const int kk = kb + 4*u;
      if (mrow){
        float4 h0 = ld4(hs + (size_t)gmA*Cc + kk);
        float4 mx = ld4(mrow + kk);
        float4 hp = make_float4(0.f,0.f,0.f,0.f);
        if ((gmA & (Tt-1)) != 0) hp = ld4(hs + (size_t)(gmA-1)*Cc + kk);
        pa[u].x = h0.x + (hp.x - h0.x)*mx.x;
        pa[u].y = h0.y + (hp.y - h0.y)*mx.y;
        pa[u].z = h0.z + (hp.z - h0.z)*mx.z;
        pa[u].w = h0.w + (hp.w - h0.w)*mx.w;
      } else {
        pa[u] = ld4(d.A + (size_t)gmA*K + kk);
      }
    }
    pwh[0] = *(const uint4*)(WH + (size_t)gnB*K + kb);
    pwh[1] = *(const uint4*)(WH + (size_t)gnB*K + kb + 8);
    pwl[0] = *(const uint4*)(WL + (size_t)gnB*K + kb);
    pwl[1] = *(const uint4*)(WL + (size_t)gnB*K + kb + 8);
  };

  const int wv = tid >> 6, lane = tid & 63;
  const int wm = (wv >> 1) << 6, wn = (wv & 1) << 6;
  const int fr = lane & 15;
  const int fk = (lane >> 4) << 3;

  f32x4 acc[4][4];
  const f32x4 z4 = {0.f,0.f,0.f,0.f};
  #pragma unroll
  for (int i=0;i<4;++i)
    #pragma unroll
    for (int j=0;j<4;++j) acc[i][j]=z4;

  const int nslab = K >> 5;
  load_slab(0);
  for (int kt=0; kt<nslab; ++kt){
    __syncthreads();
    {
      unsigned hw[8], lw[8];
      #pragma unroll
      for (int u=0;u<4;++u){
        const float xs[4] = {pa[u].x, pa[u].y, pa[u].z, pa[u].w};
        #pragma unroll
        for (int c=0;c<2;++c){
          unsigned u0 = __float_as_uint(xs[2*c]);
          unsigned u1 = __float_as_uint(xs[2*c+1]);
          float l0 = xs[2*c]   - __uint_as_float(u0 & 0xFFFF0000u);
          float l1 = xs[2*c+1] - __uint_as_float(u1 & 0xFFFF0000u);
          hw[u*2+c] = (u0>>16) | (u1 & 0xFFFF0000u);
          lw[u*2+c] = (__float_as_uint(l0)>>16) | (__float_as_uint(l1) & 0xFFFF0000u);
        }
      }
      uint4 t;
      t.x=hw[0];t.y=hw[1];t.z=hw[2];t.w=hw[3]; *(uint4*)&Ah[sr*LDBS+sk]   = t;
      t.x=hw[4];t.y=hw[5];t.z=hw[6];t.w=hw[7]; *(uint4*)&Ah[sr*LDBS+sk+8] = t;
      t.x=lw[0];t.y=lw[1];t.z=lw[2];t.w=lw[3]; *(uint4*)&Al[sr*LDBS+sk]   = t;
      t.x=lw[4];t.y=lw[5];t.z=lw[6];t.w=lw[7]; *(uint4*)&Al[sr*LDBS+sk+8] = t;
      *(uint4*)&Bh[sr*LDBS+sk]   = pwh[0];
      *(uint4*)&Bh[sr*LDBS+sk+8] = pwh[1];
      *(uint4*)&Bl[sr*LDBS+sk]   = pwl[0];
      *(uint4*)&Bl[sr*LDBS+sk+8] = pwl[1];
    }
    __syncthreads();
    if (kt+1 < nslab) load_slab(kt+1);

    short8 bh4[4], bl4[4];
    #pragma unroll
    for (int nt=0;nt<4;++nt){
      bh4[nt] = *(const short8*)&Bh[(wn + nt*16 + fr)*LDBS + fk];
      bl4[nt] = *(const short8*)&Bl[(wn + nt*16 + fr)*LDBS + fk];
    }
    #pragma unroll
    for (int mt=0;mt<4;++mt){
      const short8 ah = *(const short8*)&Ah[(wm + mt*16 + fr)*LDBS + fk];
      const short8 al = *(const short8*)&Al[(wm + mt*16 + fr)*LDBS + fk];
      #pragma unroll
      for (int nt=0;nt<4;++nt)
        acc[mt][nt] = __builtin_amdgcn_mfma_f32_16x16x32_bf16(ah, bh4[nt], acc[mt][nt], 0,0,0);
      #pragma unroll
      for (int nt=0;nt<4;++nt)
        acc[mt][nt] = __builtin_amdgcn_mfma_f32_16x16x32_bf16(ah, bl4[nt], acc[mt][nt], 0,0,0);
      #pragma unroll
      for (int nt=0;nt<4;++nt)
        acc[mt][nt] = __builtin_amdgcn_mfma_f32_16x16x32_bf16(al, bh4[nt], acc[mt][nt], 0,0,0);
    }
  }

  #pragma unroll
  for (int mt=0;mt<4;++mt){
    #pragma unroll
    for (int nt=0;nt<4;++nt){
      #pragma unroll
      for (int r=0;r<4;++r){
        const int row = wm + mt*16 + ((lane>>4)<<2) + r;
        const int col = wn + nt*16 + fr;
        d.out[(size_t)(m0+row)*d.N + n0 + col] = acc[mt][nt][r];
      }
    }
  }
}

// ---------------- per-head prep (in-place coefficient precompute) ----------------
__global__ __launch_bounds__(256) void head_prep(
    float* kbuf, float* awbuf, float* svwbuf, float* wbbuf, float* vbuf,
    const float* __restrict__ vfirst,
    const float* __restrict__ k_k, const float* __restrict__ k_a)
{
  const int gid = blockIdx.x*4 + (threadIdx.x>>6);
  const int e = threadIdx.x & 63;
  const int m = gid >> 4;
  const int h = gid & 15;
  const int c = h*Dd + e;
  const size_t idx = (size_t)m*Cc + c;
  const float kv0 = kbuf[idx];
  const float av  = awbuf[idx];
  const float sv  = svwbuf[idx];
  const float wv  = wbbuf[idx];
  const float v0  = vbuf[idx];
  const float vf  = vfirst[idx];
  const float kku = kv0 * k_k[c];
  const float ss  = wredsum(kku*kku);
  const float kkn = kku / fmaxf(sqrtf(ss), 1e-12f);
  const float ew  = expf(wv);
  kbuf[idx]  = kv0 * (1.f + (av - 1.f)*k_a[c]);
  awbuf[idx] = ew;
  svwbuf[idx]= -kkn * ew;
  wbbuf[idx] = kkn * av;
  vbuf[idx]  = v0 + sv*(vf - v0);
}

// ---------------- sequential scan v7: DPP + 2 blocks/CU ----------------
// 512 one-wave blocks, 16 per (b,h) chain (block owns 4 columns), so 2 blocks
// are co-resident per CU: the second wave fills the exposed LDS/dep latency
// that limited v5 (1 wave/CU, 562 cyc/step at 11% VALUBusy).
// lane = es*16 + rd: es = column slot (0..3), rd = row quad (rows 4rd..4rd+3)
// -> reduction group is 16 consecutive lanes = pure-DPP dsum16.
// Per step per lane: 4 c-reads (b128) + 1 r-read (b128) + 1 v-read, all
// 2-way-bank (free) via the d-skew addr(d) = 4d + 4*(d>>3).
// Chain's 16 blocks are %32-congruent -> same XCD -> 16x coefficient reuse
// served by that XCD's L2.
#define C4ST 292   // dword stride per step of C4 block (292 % 32 = 4)
#define RST  100   // dword stride per step of R block
__global__ __launch_bounds__(64) void scan_kernel(
    const float* __restrict__ lawb, const float* __restrict__ ewb,
    const float* __restrict__ bbb,  const float* __restrict__ kb,
    const float* __restrict__ rb,   const float* __restrict__ vb,
    float* __restrict__ outp)
{
  const int blk  = blockIdx.x;
  const int bh   = blk & 31;        // chain id; 16 blocks %32-congruent -> same XCD
  const int blkc = blk >> 5;        // 0..15: column quad
  const int b = bh >> 4, h = bh & 15;
  const int lane = threadIdx.x;
  const int es = lane >> 4;         // column slot 0..3
  const int rd = lane & 15;         // row quad (rows 4rd..4rd+3)
  const int c0 = blkc * 4;
  const int hb = h * Dd;

  __shared__ float C4L[16*C4ST];    // (law,ew,bb,k) per (t,d), d-skewed
  __shared__ float RL[16*RST];      // r per (t,d), d-skewed
  __shared__ float VL[16*4];        // v per (t, block column)

  float S[4];
  #pragma unroll
  for (int j=0;j<4;++j) S[j]=0.f;

  const size_t mbase = (size_t)b*Tt;
  const int g = lane >> 2, q = lane & 3;   // staging: step g, quad q

  float4 pl[4], pe[4], pb4[4], pk[4], pr[4];
  float pv = 0.f;
  auto prefetch = [&](int batch){
    if (batch < Tt/16){
      const size_t rowb = (mbase + (size_t)batch*16 + g)*Cc + hb;
      #pragma unroll
      for (int u=0;u<4;++u){
        const int d0 = 4*q + 16*u;
        pl[u]  = ld4(lawb + rowb + d0);
        pe[u]  = ld4(ewb  + rowb + d0);
        pb4[u] = ld4(bbb  + rowb + d0);
        pk[u]  = ld4(kb   + rowb + d0);
        pr[u]  = ld4(rb   + rowb + d0);
      }
      pv = vb[rowb + c0 + q];
    }
  };
  prefetch(0);

  for (int batch = 0; batch < Tt/16; ++batch){
    __syncthreads();   // previous batch's compute done -> LDS reusable
    #pragma unroll
    for (int u=0;u<4;++u){
      const int d0 = 4*q + 16*u;
      const float lw[4] = {pl[u].x,  pl[u].y,  pl[u].z,  pl[u].w};
      const float ew[4] = {pe[u].x,  pe[u].y,  pe[u].z,  pe[u].w};
      const float bw[4] = {pb4[u].x, pb4[u].y, pb4[u].z, pb4[u].w};
      const float kw[4] = {pk[u].x,  pk[u].y,  pk[u].z,  pk[u].w};
      #pragma unroll
      for (int jj=0;jj<4;++jj){
        const int dg = d0 + jj;
        const int ad = g*C4ST + dg*4 + (dg>>3)*4;
        *(float4*)&C4L[ad] = make_float4(lw[jj], ew[jj], bw[jj], kw[jj]);
      }
      *(float4*)&RL[g*RST + d0 + (d0>>3)*4] = pr[u];
    }
    VL[g*4 + q] = pv;
    __syncthreads();   // staging visible
    prefetch(batch+1); // in flight under this batch's compute

    const int cbase = rd*16 + (rd>>1)*4;   // addr of d=4rd (skewed)
    const int rbase = rd*4  + (rd>>1)*4;
    #pragma unroll 4
    for (int j = 0; j < 16; ++j){
      float4 c[4];
      const int cb = j*C4ST + cbase;
      #pragma unroll
      for (int p=0;p<4;++p) c[p] = *(const float4*)&C4L[cb + 4*p];
      const float vv = VL[j*4 + es];
      float ta = fmaf(c[0].x, S[0], c[1].x*S[1]);
      float tb = fmaf(c[2].x, S[2], c[3].x*S[3]);
      ta = dsum16(ta + tb);
      #pragma unroll
      for (int p=0;p<4;++p)
        S[p] = fmaf(c[p].y, S[p], fmaf(c[p].z, ta, c[p].w*vv));
      const float4 r4 = *(const float4*)&RL[j*RST + rbase];
      float oe = fmaf(r4.x, S[0], r4.y*S[1]);
      float ob = fmaf(r4.z, S[2], r4.w*S[3]);
      oe = dsum16(oe + ob);
      if (rd == 0)
        outp[(mbase + (size_t)(batch*16 + j))*Cc + hb + c0 + es] = oe;
    }
  }
}

// ---------------- GroupNorm + correction + g gating ----------------
__global__ __launch_bounds__(256) void epilogue_kernel(
    const float* __restrict__ att, const float* __restrict__ rbuf,
    const float* __restrict__ kbuf, const float* __restrict__ vbuf,
    const float* __restrict__ gbuf,
    const float* __restrict__ r_k, const float* __restrict__ gn_w,
    const float* __restrict__ gn_b, float* __restrict__ opre)
{
  const int gid = blockIdx.x*4 + (threadIdx.x>>6);
  const int e = threadIdx.x & 63;
  const int m = gid >> 4;
  const int h = gid & 15;
  const int c = h*Dd + e;
  const size_t idx = (size_t)m*Cc + c;
  const float x  = att[idx];
  const float mu = wredsum(x) * (1.f/Dd);
  const float xd = x - mu;
  const float var = wredsum(xd*xd) * (1.f/Dd);
  const float og = xd * (1.f/sqrtf(var + GN_EPS)) * gn_w[c] + gn_b[c];
  const float rv = rbuf[idx], kv = kbuf[idx], vv = vbuf[idx];
  const float cd = wredsum(rv*kv*r_k[c]);
  opre[idx] = (og + cd*vv) * gbuf[idx];
}

extern "C" void kernel_launch(void* const* d_in, const int* in_sizes, int n_in,
                              void* d_out, int out_size, void* d_ws, size_t ws_size,
                              hipStream_t stream)
{
  (void)in_sizes; (void)n_in; (void)out_size; (void)ws_size;
  const float* hs     = (const float*)d_in[0];
  const float* vfirst = (const float*)d_in[1];
  const float* xmix   = (const float*)d_in[2];
  const float* k_k    = (const float*)d_in[3];
  const float* k_a    = (const float*)d_in[4];
  const float* r_k    = (const float*)d_in[5];
  const float* W_r    = (const float*)d_in[6];
  const float* W_k    = (const float*)d_in[7];
  const float* W_v    = (const float*)d_in[8];
  const float* W_o    = (const float*)d_in[9];
  const float* w_A    = (const float*)d_in[10];
  const float* w_B    = (const float*)d_in[11];
  const float* w_b    = (const float*)d_in[12];
  const float* a_A    = (const float*)d_in[13];
  const float* a_B    = (const float*)d_in[14];
  const float* a_b    = (const float*)d_in[15];
  const float* v_A    = (const float*)d_in[16];
  const float* v_B    = (const float*)d_in[17];
  const float* v_b    = (const float*)d_in[18];
  const float* g_A    = (const float*)d_in[19];
  const float* g_B    = (const float*)d_in[20];
  const float* gn_w   = (const float*)d_in[21];
  const float* gn_b   = (const float*)d_in[22];
  float* out = (float*)d_out;
  float* ws  = (float*)d_ws;

  const size_t MC = (size_t)Mm * Cc;
  float* Br   = ws;            // r
  float* Bw   = ws + MC;       // w -> bb (head_prep) -> o_pre (epilogue)
  float* Bk   = ws + 2*MC;     // k0 -> kfin
  float* Bkk  = ws + 3*MC;     // sv -> law
  float* Bv   = ws + 4*MC;     // v0 -> v
  float* Ba   = ws + 5*MC;     // a -> ew
  float* Batt = ws + 6*MC;     // scan output
  float* Bg   = ws + 7*MC;     // g
  float* T1w  = ws + 8*MC;
  float* T1a  = T1w + (size_t)Mm*64;
  float* T1v  = T1a + (size_t)Mm*64;
  float* T1g  = T1v + (size_t)Mm*64;   // Mm*160 floats
  unsigned short* WP = (unsigned short*)(ws + 8*MC + (size_t)Mm*352);
  unsigned short* WrH = WP + 0*(size_t)NPL, *WrL = WP + 1*(size_t)NPL;
  unsigned short* WkH = WP + 2*(size_t)NPL, *WkL = WP + 3*(size_t)NPL;
  unsigned short* WvH = WP + 4*(size_t)NPL, *WvL = WP + 5*(size_t)NPL;
  unsigned short* WoH = WP + 6*(size_t)NPL, *WoL = WP + 7*(size_t)NPL;

  dim3 blk(256,1,1);

  // L0: weight split (W_r, W_k, W_v, W_o -> bf16 hi/lo planes)
  wsplit_kernel<<<dim3(NPL/(256*4),1,4), blk, 0, stream>>>(W_r, W_k, W_v, W_o, WP);

  // L1: big projections r, k0, v0 via split-bf16 MFMA
  GemmDesc dr{nullptr, W_r, Br, nullptr, Cc, Cc, 0, 0};
  GemmDesc dk{nullptr, W_k, Bk, nullptr, Cc, Cc, 2, 0};
  GemmDesc dv{nullptr, W_v, Bv, nullptr, Cc, Cc, 3, 0};
  gemm_mfma<<<dim3(Cc/TN, Mm/TM, 3), blk, 0, stream>>>(
      dr, dk, dv, WrH, WrL, WkH, WkL, WvH, WvL, xmix, hs);

  // L2: LoRA stage-1 (w: tanh; a: none; v: none; g: sigmoid)
  GemmDesc s1w{nullptr, w_A, T1w, nullptr, 64, Cc, 1, 1};
  GemmDesc s1a{nullptr, a_A, T1a, nullptr, 64, Cc, 4, 0};
  GemmDesc s1v{nullptr, v_A, T1v, nullptr, 64, Cc, 3, 0};
  GemmDesc s1g{nullptr, g_A, T1g, nullptr, 160, Cc, 5, 2};
  gemm_kernel<<<dim3(2,32,4), blk, 0, stream>>>(s1w,s1a,s1v,s1g, xmix, hs);

  // L3: LoRA stage-2
  GemmDesc s2w{T1w, w_B, Bw,  w_b,    Cc, 64,  -1, 3};
  GemmDesc s2a{T1a, a_B, Ba,  a_b,    Cc, 64,  -1, 2};
  GemmDesc s2v{T1v, v_B, Bkk, v_b,    Cc, 64,  -1, 2};
  GemmDesc s2g{T1g, g_B, Bg,  nullptr,Cc, 160, -1, 0};
  gemm_kernel<<<dim3(8,32,4), blk, 0, stream>>>(s2w,s2a,s2v,s2g, xmix, hs);

  // L4: per-head prep; in place: Bk k0->kfin, Ba a->ew, Bkk sv->law, Bw w->bb, Bv v0->v
  head_prep<<<dim3(Mm*Hh/4), blk, 0, stream>>>(Bk, Ba, Bkk, Bw, Bv,
                                               vfirst, k_k, k_a);

  // L5: sequential scan (v7: 512 one-wave blocks, 2/CU, DPP reductions)
  scan_kernel<<<dim3(512), dim3(64), 0, stream>>>(Bkk, Ba, Bw, Bk, Br, Bv, Batt);

  // L6: groupnorm + corr + g -> o_pre (reuse Bw; bb dead after scan)
  epilogue_kernel<<<dim3(Mm*Hh/4), blk, 0, stream>>>(Batt, Br, Bk, Bv, Bg,
                                                     r_k, gn_w, gn_b, Bw);

  // L7: output projection via split-bf16 MFMA
  GemmDesc doo{Bw, W_o, out, nullptr, Cc, Cc, -1, 0};
  gemm_mfma<<<dim3(Cc/TN, Mm/TM, 1), blk, 0, stream>>>(
      doo, doo, doo, WoH, WoL, WoH, WoL, WoH, WoL, xmix, hs);
}

// Round 7
// 613.260 us; speedup vs baseline: 1.4466x; 1.1214x over previous
//
#include <hip/hip_runtime.h>
#include <math.h>

#define Bb 2
#define Tt 1024
#define Cc 1024
#define Hh 16
#define Dd 64
#define Mm (Bb*Tt)
#define DECAY_SCALE (-0.6065306597126334f)
#define GN_EPS (64e-5f)

typedef __attribute__((ext_vector_type(8))) short short8;   // 8 bf16 (4 VGPRs)
typedef __attribute__((ext_vector_type(4))) float f32x4;    // MFMA acc

struct GemmDesc {
  const float* A;      // used when mixrow < 0 (row stride = K)
  const float* W;      // (N, K) row-major
  float* out;          // (M, N) row-major
  const float* bias;   // per-n bias or nullptr
  int N, K;
  int mixrow;          // >=0: A = token-shift mix of hidden_states with x_mix[mixrow]
  int ep;              // 0 none, 1 tanh, 2 sigmoid(x+bias?), 3 DECAY*sigmoid(x+bias)
};

__device__ __forceinline__ float4 ld4(const float* p){ return *reinterpret_cast<const float4*>(p); }
__device__ __forceinline__ float sigmf(float x){ return 1.f/(1.f+expf(-x)); }

__device__ __forceinline__ float wredsum(float x){
  #pragma unroll
  for (int off=32; off>0; off>>=1) x += __shfl_xor(x, off);
  return x;
}

// 16-lane sum (lanes 16k..16k+15), pure DPP (VALU speed, no LDS pipe).
__device__ __forceinline__ float dsum16(float x){
  x += __int_as_float(__builtin_amdgcn_update_dpp(0, __float_as_int(x), 0xB1, 0xF, 0xF, true));
  x += __int_as_float(__builtin_amdgcn_update_dpp(0, __float_as_int(x), 0x4E, 0xF, 0xF, true));
  x += __int_as_float(__builtin_amdgcn_update_dpp(0, __float_as_int(x), 0x141, 0xF, 0xF, true));
  x += __int_as_float(__builtin_amdgcn_update_dpp(0, __float_as_int(x), 0x140, 0xF, 0xF, true));
  return x;
}

// async global -> LDS DMA (16 B / 4 B per lane); dest = wave-uniform base + lane*size
__device__ __forceinline__ void gl2lds16(const float* g, float* l){
  __builtin_amdgcn_global_load_lds(
      (const __attribute__((address_space(1))) unsigned int*)g,
      (__attribute__((address_space(3))) unsigned int*)l, 16, 0, 0);
}
__device__ __forceinline__ void gl2lds4(const float* g, float* l){
  __builtin_amdgcn_global_load_lds(
      (const __attribute__((address_space(1))) unsigned int*)g,
      (__attribute__((address_space(3))) unsigned int*)l, 4, 0, 0);
}

// ---------------- vector-ALU GEMM (LoRA stages only) ----------------
#define BM 64
#define BN 128
#define BK 32

__global__ __launch_bounds__(256) void gemm_kernel(
    GemmDesc d0, GemmDesc d1, GemmDesc d2, GemmDesc d3,
    const float* __restrict__ xmix, const float* __restrict__ hs)
{
  GemmDesc d = (blockIdx.z==0)?d0:(blockIdx.z==1)?d1:(blockIdx.z==2)?d2:d3;
  const int n0 = blockIdx.x * BN;
  if (n0 >= d.N) return;            // block-uniform
  const int m0 = blockIdx.y * BM;
  const int tid = threadIdx.x;
  __shared__ float As[BK][BM+4];
  __shared__ float Bs[BK][BN+4];
  const int ty = tid >> 4, tx = tid & 15;

  float acc[4][8];
  #pragma unroll
  for (int i=0;i<4;++i)
    #pragma unroll
    for (int j=0;j<8;++j) acc[i][j]=0.f;

  const int K = d.K;
  const int nt = K / BK;
  const float* mrow = (d.mixrow >= 0) ? (xmix + (size_t)d.mixrow * Cc) : nullptr;
  float4 pa[2], pb[4];

  auto load_tile = [&](int kt){
    const int kbase = kt * BK;
    #pragma unroll
    for (int u=0;u<2;++u){
      const int li = tid + u*256;
      const int ar = li >> 3;
      const int kk = ((li & 7) << 2) + kbase;
      const int gm = m0 + ar;
      if (mrow){
        float4 h0 = ld4(hs + (size_t)gm*Cc + kk);
        float4 mx = ld4(mrow + kk);
        float4 hp = make_float4(0.f,0.f,0.f,0.f);
        if ((gm & (Tt-1)) != 0) hp = ld4(hs + (size_t)(gm-1)*Cc + kk);
        pa[u].x = h0.x + (hp.x - h0.x)*mx.x;
        pa[u].y = h0.y + (hp.y - h0.y)*mx.y;
        pa[u].z = h0.z + (hp.z - h0.z)*mx.z;
        pa[u].w = h0.w + (hp.w - h0.w)*mx.w;
      } else {
        pa[u] = ld4(d.A + (size_t)gm*K + kk);
      }
    }
    #pragma unroll
    for (int u=0;u<4;++u){
      const int li = tid + u*256;
      const int br = li >> 3;
      const int kk = ((li & 7) << 2) + kbase;
      const int gn = n0 + br;
      pb[u] = (gn < d.N) ? ld4(d.W + (size_t)gn*K + kk) : make_float4(0.f,0.f,0.f,0.f);
    }
  };

  load_tile(0);
  for (int kt=0; kt<nt; ++kt){
    __syncthreads();
    #pragma unroll
    for (int u=0;u<2;++u){
      const int li = tid + u*256;
      const int ar = li >> 3;
      const int kc = (li & 7) << 2;
      As[kc+0][ar] = pa[u].x; As[kc+1][ar] = pa[u].y;
      As[kc+2][ar] = pa[u].z; As[kc+3][ar] = pa[u].w;
    }
    #pragma unroll
    for (int u=0;u<4;++u){
      const int li = tid + u*256;
      const int br = li >> 3;
      const int kc = (li & 7) << 2;
      Bs[kc+0][br] = pb[u].x; Bs[kc+1][br] = pb[u].y;
      Bs[kc+2][br] = pb[u].z; Bs[kc+3][br] = pb[u].w;
    }
    __syncthreads();
    if (kt+1 < nt) load_tile(kt+1);
    #pragma unroll
    for (int kk=0;kk<BK;++kk){
      const float4 a0 = *(const float4*)&As[kk][ty<<2];
      const float4 b0 = *(const float4*)&Bs[kk][tx<<3];
      const float4 b1 = *(const float4*)&Bs[kk][(tx<<3)+4];
      const float av[4] = {a0.x,a0.y,a0.z,a0.w};
      const float bv[8] = {b0.x,b0.y,b0.z,b0.w,b1.x,b1.y,b1.z,b1.w};
      #pragma unroll
      for (int i=0;i<4;++i)
        #pragma unroll
        for (int j=0;j<8;++j)
          acc[i][j] = fmaf(av[i], bv[j], acc[i][j]);
    }
  }

  const int ep = d.ep;
  #pragma unroll
  for (int i=0;i<4;++i){
    const int gm = m0 + (ty<<2) + i;
    float* orow = d.out + (size_t)gm * d.N;
    #pragma unroll
    for (int j=0;j<8;++j){
      const int gn = n0 + (tx<<3) + j;
      if (gn < d.N){
        float x = acc[i][j];
        if (ep==1) x = tanhf(x);
        else if (ep==2){ if (d.bias) x += d.bias[gn]; x = sigmf(x); }
        else if (ep==3){ x += d.bias[gn]; x = DECAY_SCALE * sigmf(x); }
        orow[gn] = x;
      }
    }
  }
}

// ---------------- weight split pre-pass (fp32 -> bf16 hi/lo planes) ----------------
#define NPL (Cc*Cc)
__global__ __launch_bounds__(256) void wsplit_kernel(
    const float* __restrict__ s0, const float* __restrict__ s1,
    const float* __restrict__ s2, const float* __restrict__ s3,
    unsigned short* __restrict__ planes)
{
  const int z = blockIdx.z;
  const float* src = z==0?s0:z==1?s1:z==2?s2:s3;
  unsigned short* dh = planes + (size_t)z*2*NPL;
  unsigned short* dl = dh + NPL;
  const size_t i = ((size_t)blockIdx.x*256 + threadIdx.x)*4;
  float4 v = ld4(src + i);
  const float xs[4] = {v.x, v.y, v.z, v.w};
  unsigned hw[2], lw[2];
  #pragma unroll
  for (int c=0;c<2;++c){
    unsigned u0 = __float_as_uint(xs[2*c]);
    unsigned u1 = __float_as_uint(xs[2*c+1]);
    float l0 = xs[2*c]   - __uint_as_float(u0 & 0xFFFF0000u);
    float l1 = xs[2*c+1] - __uint_as_float(u1 & 0xFFFF0000u);
    hw[c] = (u0>>16) | (u1 & 0xFFFF0000u);
    lw[c] = (__float_as_uint(l0)>>16) | (__float_as_uint(l1) & 0xFFFF0000u);
  }
  uint2 hv; hv.x = hw[0]; hv.y = hw[1];
  uint2 lv; lv.x = lw[0]; lv.y = lw[1];
  *(uint2*)(dh + i) = hv;
  *(uint2*)(dl + i) = lv;
}

// ---------------- split-bf16 MFMA GEMM (big projections) ----------------
#define TM 128
#define TN 128
#define LDBS 40   // bf16 row stride in LDS

__global__ __launch_bounds__(256) void gemm_mfma(
    GemmDesc d0, GemmDesc d1, GemmDesc d2,
    const unsigned short* __restrict__ WH0, const unsigned short* __restrict__ WL0,
    const unsigned short* __restrict__ WH1, const unsigned short* __restrict__ WL1,
    const unsigned short* __restrict__ WH2, const unsigned short* __restrict__ WL2,
    const float* __restrict__ xmix, const float* __restrict__ hs)
{
  const int z = blockIdx.z;
  GemmDesc d = z==0?d0:(z==1?d1:d2);
  const unsigned short* WH = z==0?WH0:(z==1?WH1:WH2);
  const unsigned short* WL = z==0?WL0:(z==1?WL1:WL2);
  const int m0 = blockIdx.y * TM;
  const int n0 = blockIdx.x * TN;
  const int K  = d.K;
  const int tid = threadIdx.x;

  __shared__ __align__(16) unsigned short Ah[TM*LDBS], Al[TM*LDBS];
  __shared__ __align__(16) unsigned short Bh[TN*LDBS], Bl[TN*LDBS];

  const int sr = tid >> 1;
  const int sk = (tid & 1) << 4;
  const int gmA = m0 + sr;
  const int gnB = n0 + sr;
  const float* mrow = (d.mixrow >= 0) ? (xmix + (size_t)d.mixrow * Cc) : nullptr;

  float4 pa[4];
  uint4 pwh[2], pwl[2];
  auto load_slab = [&](int kt){
    const int kb = kt*32 + sk;
    #pragma unroll
    for (int u=0;u<4;++u){
      const int kk = kb + 4*u;
      if (mrow){
        float4 h0 = ld4(hs + (size_t)gmA*Cc + kk);
        float4 mx = ld4(mrow + kk);
        float4 hp = make_float4(0.f,0.f,0.f,0.f);
        if ((gmA & (Tt-1)) != 0) hp = ld4(hs + (size_t)(gmA-1)*Cc + kk);
        pa[u].x = h0.x + (hp.x - h0.x)*mx.x;
        pa[u].y = h0.y + (hp.y - h0.y)*mx.y;
        pa[u].z = h0.z + (hp.z - h0.z)*mx.z;
        pa[u].w = h0.w + (hp.w - h0.w)*mx.w;
      } else {
        pa[u] = ld4(d.A + (size_t)gmA*K + kk);
      }
    }
    pwh[0] = *(const uint4*)(WH + (size_t)gnB*K + kb);
    pwh[1] = *(const uint4*)(WH + (size_t)gnB*K + kb + 8);
    pwl[0] = *(const uint4*)(WL + (size_t)gnB*K + kb);
    pwl[1] = *(const uint4*)(WL + (size_t)gnB*K + kb + 8);
  };

  const int wv = tid >> 6, lane = tid & 63;
  const int wm = (wv >> 1) << 6, wn = (wv & 1) << 6;
  const int fr = lane & 15;
  const int fk = (lane >> 4) << 3;

  f32x4 acc[4][4];
  const f32x4 z4 = {0.f,0.f,0.f,0.f};
  #pragma unroll
  for (int i=0;i<4;++i)
    #pragma unroll
    for (int j=0;j<4;++j) acc[i][j]=z4;

  const int nslab = K >> 5;
  load_slab(0);
  for (int kt=0; kt<nslab; ++kt){
    __syncthreads();
    {
      unsigned hw[8], lw[8];
      #pragma unroll
      for (int u=0;u<4;++u){
        const float xs[4] = {pa[u].x, pa[u].y, pa[u].z, pa[u].w};
        #pragma unroll
        for (int c=0;c<2;++c){
          unsigned u0 = __float_as_uint(xs[2*c]);
          unsigned u1 = __float_as_uint(xs[2*c+1]);
          float l0 = xs[2*c]   - __uint_as_float(u0 & 0xFFFF0000u);
          float l1 = xs[2*c+1] - __uint_as_float(u1 & 0xFFFF0000u);
          hw[u*2+c] = (u0>>16) | (u1 & 0xFFFF0000u);
          lw[u*2+c] = (__float_as_uint(l0)>>16) | (__float_as_uint(l1) & 0xFFFF0000u);
        }
      }
      uint4 t;
      t.x=hw[0];t.y=hw[1];t.z=hw[2];t.w=hw[3]; *(uint4*)&Ah[sr*LDBS+sk]   = t;
      t.x=hw[4];t.y=hw[5];t.z=hw[6];t.w=hw[7]; *(uint4*)&Ah[sr*LDBS+sk+8] = t;
      t.x=lw[0];t.y=lw[1];t.z=lw[2];t.w=lw[3]; *(uint4*)&Al[sr*LDBS+sk]   = t;
      t.x=lw[4];t.y=lw[5];t.z=lw[6];t.w=lw[7]; *(uint4*)&Al[sr*LDBS+sk+8] = t;
      *(uint4*)&Bh[sr*LDBS+sk]   = pwh[0];
      *(uint4*)&Bh[sr*LDBS+sk+8] = pwh[1];
      *(uint4*)&Bl[sr*LDBS+sk]   = pwl[0];
      *(uint4*)&Bl[sr*LDBS+sk+8] = pwl[1];
    }
    __syncthreads();
    if (kt+1 < nslab) load_slab(kt+1);

    short8 bh4[4], bl4[4];
    #pragma unroll
    for (int nt=0;nt<4;++nt){
      bh4[nt] = *(const short8*)&Bh[(wn + nt*16 + fr)*LDBS + fk];
      bl4[nt] = *(const short8*)&Bl[(wn + nt*16 + fr)*LDBS + fk];
    }
    #pragma unroll
    for (int mt=0;mt<4;++mt){
      const short8 ah = *(const short8*)&Ah[(wm + mt*16 + fr)*LDBS + fk];
      const short8 al = *(const short8*)&Al[(wm + mt*16 + fr)*LDBS + fk];
      #pragma unroll
      for (int nt=0;nt<4;++nt)
        acc[mt][nt] = __builtin_amdgcn_mfma_f32_16x16x32_bf16(ah, bh4[nt], acc[mt][nt], 0,0,0);
      #pragma unroll
      for (int nt=0;nt<4;++nt)
        acc[mt][nt] = __builtin_amdgcn_mfma_f32_16x16x32_bf16(ah, bl4[nt], acc[mt][nt], 0,0,0);
      #pragma unroll
      for (int nt=0;nt<4;++nt)
        acc[mt][nt] = __builtin_amdgcn_mfma_f32_16x16x32_bf16(al, bh4[nt], acc[mt][nt], 0,0,0);
    }
  }

  #pragma unroll
  for (int mt=0;mt<4;++mt){
    #pragma unroll
    for (int nt=0;nt<4;++nt){
      #pragma unroll
      for (int r=0;r<4;++r){
        const int row = wm + mt*16 + ((lane>>4)<<2) + r;
        const int col = wn + nt*16 + fr;
        d.out[(size_t)(m0+row)*d.N + n0 + col] = acc[mt][nt][r];
      }
    }
  }
}

// ---------------- per-head prep (in-place coefficient precompute) ----------------
__global__ __launch_bounds__(256) void head_prep(
    float* kbuf, float* awbuf, float* svwbuf, float* wbbuf, float* vbuf,
    const float* __restrict__ vfirst,
    const float* __restrict__ k_k, const float* __restrict__ k_a)
{
  const int gid = blockIdx.x*4 + (threadIdx.x>>6);
  const int e = threadIdx.x & 63;
  const int m = gid >> 4;
  const int h = gid & 15;
  const int c = h*Dd + e;
  const size_t idx = (size_t)m*Cc + c;
  const float kv0 = kbuf[idx];
  const float av  = awbuf[idx];
  const float sv  = svwbuf[idx];
  const float wv  = wbbuf[idx];
  const float v0  = vbuf[idx];
  const float vf  = vfirst[idx];
  const float kku = kv0 * k_k[c];
  const float ss  = wredsum(kku*kku);
  const float kkn = kku / fmaxf(sqrtf(ss), 1e-12f);
  const float ew  = expf(wv);
  kbuf[idx]  = kv0 * (1.f + (av - 1.f)*k_a[c]);
  awbuf[idx] = ew;
  svwbuf[idx]= -kkn * ew;
  wbbuf[idx] = kkn * av;
  vbuf[idx]  = v0 + sv*(vf - v0);
}

// ---------------- sequential scan v8: DMA double-buffer + register pipeline ----------------
// 512 one-wave blocks, 16 per (b,h) chain (block owns 4 cols). lane = es*16+rd.
// Coefficients DMA-staged (global_load_lds, raw row layout: lane-contiguous AND
// 2-way-bank-free for the 4*rd b128 reads) into a double-buffered LDS region;
// single-wave blocks => NO __syncthreads anywhere, one s_waitcnt vmcnt(0) per
// 16-step batch. Inner loop: explicit 2-buffer register pipeline — step t
// computes from regs while step t+2's ds_reads are in flight.
#define NB (Tt/16)
__global__ __launch_bounds__(64) void scan_kernel(
    const float* __restrict__ lawb, const float* __restrict__ ewb,
    const float* __restrict__ bbb,  const float* __restrict__ kb,
    const float* __restrict__ rb,   const float* __restrict__ vb,
    float* __restrict__ outp)
{
  const int blk  = blockIdx.x;
  const int bh   = blk & 31;        // chain id; 16 blocks %32-congruent -> same XCD
  const int blkc = blk >> 5;        // 0..15: column quad
  const int b = bh >> 4, h = bh & 15;
  const int lane = threadIdx.x;
  const int es = lane >> 4;         // column slot 0..3
  const int rd = lane & 15;         // row quad (rows 4rd..4rd+3)
  const int colb = blkc * 4;
  const int hb = h * Dd;
  const int la = 4*rd;              // dword offset of this lane's row quad

  // per buffer: law[1024] ew[1024] bb[1024] k[1024] r[1024] v[64]
  __shared__ __align__(16) float LB[2][5*1024 + 64];

  float S0=0.f, S1=0.f, S2=0.f, S3=0.f;
  const size_t mbase = (size_t)b*Tt;

  const int qrow = lane >> 4;           // staging: row within 4-row slab
  const int qcol = (lane & 15) * 4;     // staging: dword col

  auto stage = [&](int bt){
    const size_t g0 = (mbase + (size_t)bt*16)*Cc + hb;
    float* dst = &LB[bt&1][0];
    const float* srcs[5] = {lawb, ewb, bbb, kb, rb};
    #pragma unroll
    for (int a=0;a<5;++a){
      const float* s = srcs[a] + g0 + (size_t)qrow*Cc + qcol;
      #pragma unroll
      for (int i=0;i<4;++i)
        gl2lds16(s + (size_t)(4*i)*Cc, dst + a*1024 + i*256);
    }
    gl2lds4(vb + g0 + (size_t)(lane>>2)*Cc + colb + (lane&3), dst + 5120);
  };

  stage(0);

  for (int bt = 0; bt < NB; ++bt){
    __builtin_amdgcn_s_waitcnt(0x0F70);   // vmcnt(0): batch bt's DMA complete
    if (bt+1 < NB) stage(bt+1);           // in flight under this batch's compute
    const float* cb2 = &LB[bt&1][0];

    float4 LwA,EwA,BqA,KqA,RqA, LwB,EwB,BqB,KqB,RqB;
    float VvA, VvB;
    auto ldq = [&](int t, float4&Lw, float4&Ew, float4&Bq, float4&Kq, float4&Rq, float&Vv){
      Lw = *(const float4*)&cb2[         t*64 + la];
      Ew = *(const float4*)&cb2[1024 + t*64 + la];
      Bq = *(const float4*)&cb2[2048 + t*64 + la];
      Kq = *(const float4*)&cb2[3072 + t*64 + la];
      Rq = *(const float4*)&cb2[4096 + t*64 + la];
      Vv = cb2[5120 + t*4 + es];
    };
    ldq(0, LwA,EwA,BqA,KqA,RqA,VvA);
    ldq(1, LwB,EwB,BqB,KqB,RqB,VvB);

    auto stepf = [&](int t, float4&Lw, float4&Ew, float4&Bq, float4&Kq, float4&Rq, float&Vv){
      const float4 rr = Rq;
      const float vv = Vv;
      float ta = fmaf(Lw.y, S1, Lw.x*S0);
      float tb = fmaf(Lw.w, S3, Lw.z*S2);
      ta = dsum16(ta + tb);
      S0 = fmaf(Ew.x, S0, fmaf(Bq.x, ta, Kq.x*vv));
      S1 = fmaf(Ew.y, S1, fmaf(Bq.y, ta, Kq.y*vv));
      S2 = fmaf(Ew.z, S2, fmaf(Bq.z, ta, Kq.z*vv));
      S3 = fmaf(Ew.w, S3, fmaf(Bq.w, ta, Kq.w*vv));
      if (t+2 < 16) ldq(t+2, Lw,Ew,Bq,Kq,Rq,Vv);   // refill freed buffer
      float oe = fmaf(rr.y, S1, rr.x*S0);
      float ob = fmaf(rr.w, S3, rr.z*S2);
      oe = dsum16(oe + ob);
      if (rd == 0)
        outp[(mbase + (size_t)(bt*16 + t))*Cc + hb + colb + es] = oe;
    };

    #pragma unroll
    for (int t = 0; t < 16; ++t){
      if (t & 1) stepf(t, LwB,EwB,BqB,KqB,RqB,VvB);
      else       stepf(t, LwA,EwA,BqA,KqA,RqA,VvA);
    }
  }
}

// ---------------- GroupNorm + correction + g gating ----------------
__global__ __launch_bounds__(256) void epilogue_kernel(
    const float* __restrict__ att, const float* __restrict__ rbuf,
    const float* __restrict__ kbuf, const float* __restrict__ vbuf,
    const float* __restrict__ gbuf,
    const float* __restrict__ r_k, const float* __restrict__ gn_w,
    const float* __restrict__ gn_b, float* __restrict__ opre)
{
  const int gid = blockIdx.x*4 + (threadIdx.x>>6);
  const int e = threadIdx.x & 63;
  const int m = gid >> 4;
  const int h = gid & 15;
  const int c = h*Dd + e;
  const size_t idx = (size_t)m*Cc + c;
  const float x  = att[idx];
  const float mu = wredsum(x) * (1.f/Dd);
  const float xd = x - mu;
  const float var = wredsum(xd*xd) * (1.f/Dd);
  const float og = xd * (1.f/sqrtf(var + GN_EPS)) * gn_w[c] + gn_b[c];
  const float rv = rbuf[idx], kv = kbuf[idx], vv = vbuf[idx];
  const float cd = wredsum(rv*kv*r_k[c]);
  opre[idx] = (og + cd*vv) * gbuf[idx];
}

extern "C" void kernel_launch(void* const* d_in, const int* in_sizes, int n_in,
                              void* d_out, int out_size, void* d_ws, size_t ws_size,
                              hipStream_t stream)
{
  (void)in_sizes; (void)n_in; (void)out_size; (void)ws_size;
  const float* hs     = (const float*)d_in[0];
  const float* vfirst = (const float*)d_in[1];
  const float* xmix   = (const float*)d_in[2];
  const float* k_k    = (const float*)d_in[3];
  const float* k_a    = (const float*)d_in[4];
  const float* r_k    = (const float*)d_in[5];
  const float* W_r    = (const float*)d_in[6];
  const float* W_k    = (const float*)d_in[7];
  const float* W_v    = (const float*)d_in[8];
  const float* W_o    = (const float*)d_in[9];
  const float* w_A    = (const float*)d_in[10];
  const float* w_B    = (const float*)d_in[11];
  const float* w_b    = (const float*)d_in[12];
  const float* a_A    = (const float*)d_in[13];
  const float* a_B    = (const float*)d_in[14];
  const float* a_b    = (const float*)d_in[15];
  const float* v_A    = (const float*)d_in[16];
  const float* v_B    = (const float*)d_in[17];
  const float* v_b    = (const float*)d_in[18];
  const float* g_A    = (const float*)d_in[19];
  const float* g_B    = (const float*)d_in[20];
  const float* gn_w   = (const float*)d_in[21];
  const float* gn_b   = (const float*)d_in[22];
  float* out = (float*)d_out;
  float* ws  = (float*)d_ws;

  const size_t MC = (size_t)Mm * Cc;
  float* Br   = ws;            // r
  float* Bw   = ws + MC;       // w -> bb (head_prep) -> o_pre (epilogue)
  float* Bk   = ws + 2*MC;     // k0 -> kfin
  float* Bkk  = ws + 3*MC;     // sv -> law
  float* Bv   = ws + 4*MC;     // v0 -> v
  float* Ba   = ws + 5*MC;     // a -> ew
  float* Batt = ws + 6*MC;     // scan output
  float* Bg   = ws + 7*MC;     // g
  float* T1w  = ws + 8*MC;
  float* T1a  = T1w + (size_t)Mm*64;
  float* T1v  = T1a + (size_t)Mm*64;
  float* T1g  = T1v + (size_t)Mm*64;   // Mm*160 floats
  unsigned short* WP = (unsigned short*)(ws + 8*MC + (size_t)Mm*352);
  unsigned short* WrH = WP + 0*(size_t)NPL, *WrL = WP + 1*(size_t)NPL;
  unsigned short* WkH = WP + 2*(size_t)NPL, *WkL = WP + 3*(size_t)NPL;
  unsigned short* WvH = WP + 4*(size_t)NPL, *WvL = WP + 5*(size_t)NPL;
  unsigned short* WoH = WP + 6*(size_t)NPL, *WoL = WP + 7*(size_t)NPL;

  dim3 blk(256,1,1);

  // L0: weight split (W_r, W_k, W_v, W_o -> bf16 hi/lo planes)
  wsplit_kernel<<<dim3(NPL/(256*4),1,4), blk, 0, stream>>>(W_r, W_k, W_v, W_o, WP);

  // L1: big projections r, k0, v0 via split-bf16 MFMA
  GemmDesc dr{nullptr, W_r, Br, nullptr, Cc, Cc, 0, 0};
  GemmDesc dk{nullptr, W_k, Bk, nullptr, Cc, Cc, 2, 0};
  GemmDesc dv{nullptr, W_v, Bv, nullptr, Cc, Cc, 3, 0};
  gemm_mfma<<<dim3(Cc/TN, Mm/TM, 3), blk, 0, stream>>>(
      dr, dk, dv, WrH, WrL, WkH, WkL, WvH, WvL, xmix, hs);

  // L2: LoRA stage-1 (w: tanh; a: none; v: none; g: sigmoid)
  GemmDesc s1w{nullptr, w_A, T1w, nullptr, 64, Cc, 1, 1};
  GemmDesc s1a{nullptr, a_A, T1a, nullptr, 64, Cc, 4, 0};
  GemmDesc s1v{nullptr, v_A, T1v, nullptr, 64, Cc, 3, 0};
  GemmDesc s1g{nullptr, g_A, T1g, nullptr, 160, Cc, 5, 2};
  gemm_kernel<<<dim3(2,32,4), blk, 0, stream>>>(s1w,s1a,s1v,s1g, xmix, hs);

  // L3: LoRA stage-2
  GemmDesc s2w{T1w, w_B, Bw,  w_b,    Cc, 64,  -1, 3};
  GemmDesc s2a{T1a, a_B, Ba,  a_b,    Cc, 64,  -1, 2};
  GemmDesc s2v{T1v, v_B, Bkk, v_b,    Cc, 64,  -1, 2};
  GemmDesc s2g{T1g, g_B, Bg,  nullptr,Cc, 160, -1, 0};
  gemm_kernel<<<dim3(8,32,4), blk, 0, stream>>>(s2w,s2a,s2v,s2g, xmix, hs);

  // L4: per-head prep; in place: Bk k0->kfin, Ba a->ew, Bkk sv->law, Bw w->bb, Bv v0->v
  head_prep<<<dim3(Mm*Hh/4), blk, 0, stream>>>(Bk, Ba, Bkk, Bw, Bv,
                                               vfirst, k_k, k_a);

  // L5: sequential scan (v8: DMA double-buffer, no barriers, reg pipeline)
  scan_kernel<<<dim3(512), dim3(64), 0, stream>>>(Bkk, Ba, Bw, Bk, Br, Bv, Batt);

  // L6: groupnorm + corr + g -> o_pre (reuse Bw; bb dead after scan)
  epilogue_kernel<<<dim3(Mm*Hh/4), blk, 0, stream>>>(Batt, Br, Bk, Bv, Bg,
                                                     r_k, gn_w, gn_b, Bw);

  // L7: output projection via split-bf16 MFMA
  GemmDesc doo{Bw, W_o, out, nullptr, Cc, Cc, -1, 0};
  gemm_mfma<<<dim3(Cc/TN, Mm/TM, 1), blk, 0, stream>>>(
      doo, doo, doo, WoH, WoL, WoH, WoL, WoH, WoL, xmix, hs);
}